// Round 7
// baseline (198.049 us; speedup 1.0000x reference)
//
#include <hip/hip_runtime.h>
#include <math.h>

#define NB   4
#define NSEQ 8192
#define CDIM 64
#define M    2048
#define NW   7
#define NBLK2 72     // 8-step kv-chunks per window: sum_QT ((QT>>1)+1) = 72

typedef _Float16 half8 __attribute__((ext_vector_type(8)));
typedef __fp16 fp16x2 __attribute__((ext_vector_type(2)));   // native cvt_pkrtz type
typedef float f32x4 __attribute__((ext_vector_type(4)));
typedef unsigned short u16x4 __attribute__((ext_vector_type(4)));

#if defined(__has_builtin) && __has_builtin(__builtin_amdgcn_exp2f)
#define EXP2(x) __builtin_amdgcn_exp2f(x)
#else
#define EXP2(x) __expf((x) * 0.69314718056f)
#endif

// Q pre-scale: 1/sqrt(64) * log2(e) folded into Wq's B-frags so attn uses raw exp2
#define QSCALE 0.1803368801111204f
// exp bias: p = exp2(s' - PBIAS) keeps P under f16 max; scales P and l by
// 2^-PBIAS uniformly -> ratios invariant in the linear mix.
#define PBIAS 4.0f

// attn LDS (10240 B total — K is GONE from LDS, V dbuf only):
//   [0,10240): Vt dbuf, 2 x 64 rows x 80B stride, pair-packed
//              pi: word u of lane-quad Q = (V[kv=4Q+u], V[kv=4Q+u+16]),
//              chunk-XOR h(d)=(d>>4)^(d&3)^((d>>2)&3); stride 80 spreads
//              the b32 staging writes over all 32 banks.
// K is loaded per-wave straight from global into registers (1-step prefetch,
// named kbA/kbB sets, 2-unrolled loop — spans are always even). The K frag
// kb[ns][h] for lane (quad,l15) = K[kt*32+ns*16+l15][quad*8+32h .. +8] —
// identical addressing to the Q loads; all 4 waves read the same 2KB -> L1.
// This removes K's staging writes, its ds_reads, and its barrier dependency
// from the per-step serial chain; the barrier protects only the V dbuf.
// LAUNCH BOUNDS: (256,4). DO NOT raise the 2nd arg — measured twice (prev
// session + R2): allocator squeezes below the live set and spills accs to
// scratch (FETCH +190MB, attn 50->117us). (256,4) caps alloc at 128 VGPR.
#define VT_STRIDE 80
#define VT_BUF  5120

__device__ __forceinline__ int win_base(int w) {
    return (w < 4) ? (w << 11) : ((w < 6) ? ((w - 4) << 12) : 0);
}
__device__ __forceinline__ int win_stride(int w) {
    return (w < 4) ? 1 : ((w < 6) ? 2 : 4);
}

// ---------------- kernel 1: QKV projection via MFMA, f16 outputs ----------
__global__ __launch_bounds__(256, 1) void qkv_proj(
        const float* __restrict__ x,
        const float* __restrict__ Wq, const float* __restrict__ Wk,
        const float* __restrict__ Wv,
        _Float16* __restrict__ Qg, _Float16* __restrict__ Kg,
        _Float16* __restrict__ Vg) {
    const int t = threadIdx.x;
    const int wid = t >> 6, lane = t & 63, l15 = lane & 15, quad = lane >> 4;

    // ---- one-time: W -> B-frags (f32 load, scale Q, cvt to f16) ----
    half8 wb[3][2][4];
#pragma unroll
    for (int m = 0; m < 3; ++m) {
        const float* Wm = (m == 0) ? Wq : ((m == 1) ? Wk : Wv);
        const float sc = (m == 0) ? QSCALE : 1.0f;
#pragma unroll
        for (int kh = 0; kh < 2; ++kh)
#pragma unroll
            for (int nt = 0; nt < 4; ++nt) {
                float f[8];
#pragma unroll
                for (int j = 0; j < 8; ++j)
                    f[j] = Wm[(kh * 32 + quad * 8 + j) * 64 + nt * 16 + l15] * sc;
                union { fp16x2 h[4]; half8 v; } u;
#pragma unroll
                for (int p = 0; p < 4; ++p)
                    u.h[p] = __builtin_amdgcn_cvt_pkrtz(f[2 * p], f[2 * p + 1]);
                wb[m][kh][nt] = u.v;
            }
    }

    const int rowbase = blockIdx.x * 128 + wid * 32;
#pragma unroll
    for (int mt = 0; mt < 2; ++mt) {
        const int r0 = rowbase + mt * 16;
        // A-frags: X rows (r0+l15), f32 -> f16
        half8 xa[2];
#pragma unroll
        for (int kh = 0; kh < 2; ++kh) {
            const float* xr = x + (size_t)(r0 + l15) * 64 + kh * 32 + quad * 8;
            const float4 a = *(const float4*)xr;
            const float4 b2 = *(const float4*)(xr + 4);
            union { fp16x2 h[4]; half8 v; } u;
            u.h[0] = __builtin_amdgcn_cvt_pkrtz(a.x, a.y);
            u.h[1] = __builtin_amdgcn_cvt_pkrtz(a.z, a.w);
            u.h[2] = __builtin_amdgcn_cvt_pkrtz(b2.x, b2.y);
            u.h[3] = __builtin_amdgcn_cvt_pkrtz(b2.z, b2.w);
            xa[kh] = u.v;
        }
#pragma unroll
        for (int m = 0; m < 3; ++m) {
            f32x4 acc[4];
#pragma unroll
            for (int nt = 0; nt < 4; ++nt) {
                acc[nt] = (f32x4){0.f, 0.f, 0.f, 0.f};
                acc[nt] = __builtin_amdgcn_mfma_f32_16x16x32_f16(xa[0], wb[m][0][nt], acc[nt], 0, 0, 0);
                acc[nt] = __builtin_amdgcn_mfma_f32_16x16x32_f16(xa[1], wb[m][1][nt], acc[nt], 0, 0, 0);
            }
            _Float16* outp = (m == 0) ? Qg : ((m == 1) ? Kg : Vg);
#pragma unroll
            for (int nt = 0; nt < 4; ++nt)
#pragma unroll
                for (int j = 0; j < 4; ++j)
                    outp[(size_t)(r0 + quad * 4 + j) * 64 + nt * 16 + l15] =
                        (_Float16)acc[nt][j];
        }
    }
}

// ---------------- kernel 2: flash attention, 128q tile x 8 k-steps --------
// R17 (resubmit): K-from-global (register prefetch), V-only LDS.
struct AttnState {
    const _Float16* Qb; const _Float16* Kb; const _Float16* Vb;
    int base, stride, QT, kt1;
    int wid, l15, quad, kq, vd0;
    half8 qa00, qa01, qa10, qa11;
    f32x4 oacc0[4], oacc1[4];
    float l0, l1;
    u16x4 pv0, pv1;
    char* smem;
};

__device__ __forceinline__ void loadK(AttnState& s, half8 kb[2][2], int kt) {
#pragma unroll
    for (int ns = 0; ns < 2; ++ns) {
        const size_t kr =
            (size_t)(s.base + s.stride * (kt * 32 + ns * 16 + s.l15)) * 64;
        kb[ns][0] = *(const half8*)(s.Kb + kr + s.quad * 8);
        kb[ns][1] = *(const half8*)(s.Kb + kr + 32 + s.quad * 8);
    }
}

__device__ __forceinline__ void loadV(AttnState& s, int kt) {
    const size_t va = (size_t)(s.base + s.stride * (kt * 32 + s.kq)) * 64 + s.vd0;
    s.pv0 = *(const u16x4*)(s.Vb + va);
    s.pv1 = *(const u16x4*)(s.Vb + va + (size_t)s.stride * 16 * 64);
}

template <int CUR>
__device__ __forceinline__ void writeV(AttnState& s) {
    char* Vn = s.smem + CUR * VT_BUF;
#pragma unroll
    for (int i = 0; i < 4; ++i) {
        int d = s.vd0 + i;
        unsigned int pkw = (unsigned int)s.pv0[i] | ((unsigned int)s.pv1[i] << 16);
        int ch = ((s.kq >> 2) ^ (d >> 4) ^ (d & 3) ^ ((d >> 2) & 3)) & 3;
        *(unsigned int*)(Vn + d * VT_STRIDE + ch * 16 + (s.kq & 3) * 4) = pkw;
    }
}

template <int CUR>
__device__ __forceinline__ void stepAttn(AttnState& s, int kt,
                                         half8 kbC[2][2], half8 kbN[2][2]) {
    const bool pf = (kt + 1 < s.kt1);
    if (pf) {
        loadK(s, kbN, kt + 1);
        loadV(s, kt + 1);
    }
    const char* Vd = s.smem + CUR * VT_BUF;
    half8 vb[4];
#pragma unroll
    for (int ns = 0; ns < 4; ++ns) {
        const int d = ns * 16 + s.l15;
        const int ch = (s.quad ^ (d >> 4) ^ (d & 3) ^ ((d >> 2) & 3)) & 3;
        vb[ns] = *(const half8*)(Vd + d * VT_STRIDE + ch * 16);
    }
    f32x4 sa0[2], sa1[2];
    __builtin_amdgcn_s_setprio(1);
#pragma unroll
    for (int ns = 0; ns < 2; ++ns) {
        f32x4 c0 = (f32x4){0.f, 0.f, 0.f, 0.f};
        c0 = __builtin_amdgcn_mfma_f32_16x16x32_f16(kbC[ns][0], s.qa00, c0, 0, 0, 0);
        c0 = __builtin_amdgcn_mfma_f32_16x16x32_f16(kbC[ns][1], s.qa01, c0, 0, 0, 0);
        sa0[ns] = c0;
        f32x4 c1 = (f32x4){0.f, 0.f, 0.f, 0.f};
        c1 = __builtin_amdgcn_mfma_f32_16x16x32_f16(kbC[ns][0], s.qa10, c1, 0, 0, 0);
        c1 = __builtin_amdgcn_mfma_f32_16x16x32_f16(kbC[ns][1], s.qa11, c1, 0, 0, 0);
        sa1[ns] = c1;
    }
    __builtin_amdgcn_s_setprio(0);
    if (kt >= 4 * s.QT) {   // causal region (last 4 steps of the tile)
        const int q0 = s.QT * 128 + 16 * s.wid + s.l15 - kt * 32;
        const int kvb = s.quad * 4;
#pragma unroll
        for (int ns = 0; ns < 2; ++ns)
#pragma unroll
            for (int j = 0; j < 4; ++j) {
                if (kvb + ns * 16 + j > q0)      sa0[ns][j] = -1e30f;
                if (kvb + ns * 16 + j > q0 + 64) sa1[ns][j] = -1e30f;
            }
    }
    {
        union { fp16x2 h[4]; half8 v; } pu;
#pragma unroll
        for (int u = 0; u < 4; ++u) {
            float pA = EXP2(sa0[0][u] - PBIAS);   // kv = 4*quad+u
            float pB = EXP2(sa0[1][u] - PBIAS);   // kv = 4*quad+u+16
            s.l0 += pA + pB;
            pu.h[u] = __builtin_amdgcn_cvt_pkrtz(pA, pB);
        }
        __builtin_amdgcn_s_setprio(1);
#pragma unroll
        for (int ns = 0; ns < 4; ++ns)
            s.oacc0[ns] = __builtin_amdgcn_mfma_f32_16x16x32_f16(pu.v, vb[ns], s.oacc0[ns], 0, 0, 0);
        __builtin_amdgcn_s_setprio(0);
    }
    {
        union { fp16x2 h[4]; half8 v; } pu;
#pragma unroll
        for (int u = 0; u < 4; ++u) {
            float pA = EXP2(sa1[0][u] - PBIAS);
            float pB = EXP2(sa1[1][u] - PBIAS);
            s.l1 += pA + pB;
            pu.h[u] = __builtin_amdgcn_cvt_pkrtz(pA, pB);
        }
        __builtin_amdgcn_s_setprio(1);
#pragma unroll
        for (int ns = 0; ns < 4; ++ns)
            s.oacc1[ns] = __builtin_amdgcn_mfma_f32_16x16x32_f16(pu.v, vb[ns], s.oacc1[ns], 0, 0, 0);
        __builtin_amdgcn_s_setprio(0);
    }
    if (pf) writeV<CUR ^ 1>(s);
    __syncthreads();
}

__global__ __launch_bounds__(256, 4) void attn(
        const _Float16* __restrict__ Qg, const _Float16* __restrict__ Kg,
        const _Float16* __restrict__ Vg,
        _Float16* __restrict__ Op, float* __restrict__ Lp) {
    __shared__ __align__(16) char smem[10240];

    // decode (QT, ci): idx ascending in QT; blockIdx reversed -> heavy first
    const int idx = (NBLK2 - 1) - (int)blockIdx.x;
    int QT = 0;
    // cum(QT) table: 0,1,2,4,6,9,12,16,20,25,30,36,42,49,56,64
    QT += (idx >= 1);  QT += (idx >= 2);  QT += (idx >= 4);  QT += (idx >= 6);
    QT += (idx >= 9);  QT += (idx >= 12); QT += (idx >= 16); QT += (idx >= 20);
    QT += (idx >= 25); QT += (idx >= 30); QT += (idx >= 36); QT += (idx >= 42);
    QT += (idx >= 49); QT += (idx >= 56); QT += (idx >= 64);
    const int k2 = QT >> 1;
    const int cb = (QT & 1) ? (k2 + 1) * (k2 + 1) : k2 * (k2 + 1);
    const int ci = idx - cb;
    const int w = blockIdx.y, b = blockIdx.z;
    const int base = win_base(w), stride = win_stride(w);
    const int outblk = (b * NW + w) * NBLK2 + cb + ci;
    const int kt0 = ci * 8;                  // 32-col steps
    const int ktmax = 4 * QT + 4;
    const int kt1 = (kt0 + 8 < ktmax) ? kt0 + 8 : ktmax;   // span always EVEN

    const int t = threadIdx.x;
    const int wid = t >> 6, lane = t & 63, l15 = lane & 15, quad = lane >> 4;

    AttnState s;
    s.Qb = Qg + (size_t)b * NSEQ * 64;
    s.Kb = Kg + (size_t)b * NSEQ * 64;
    s.Vb = Vg + (size_t)b * NSEQ * 64;
    s.base = base; s.stride = stride; s.QT = QT; s.kt1 = kt1;
    s.wid = wid; s.l15 = l15; s.quad = quad;
    s.kq = t >> 4; s.vd0 = 4 * (t & 15);
    s.smem = smem;
    s.l0 = 0.f; s.l1 = 0.f;

    // Q frags for both strips, load once; used as MFMA *B* operand
    const size_t qr0 = (size_t)(base + stride * (QT * 128 + 16 * wid + l15)) * 64;
    const size_t qr1 = (size_t)(base + stride * (QT * 128 + 64 + 16 * wid + l15)) * 64;
    s.qa00 = *(const half8*)(s.Qb + qr0 + quad * 8);
    s.qa01 = *(const half8*)(s.Qb + qr0 + 32 + quad * 8);
    s.qa10 = *(const half8*)(s.Qb + qr1 + quad * 8);
    s.qa11 = *(const half8*)(s.Qb + qr1 + 32 + quad * 8);

#pragma unroll
    for (int ns = 0; ns < 4; ++ns) {
        s.oacc0[ns] = (f32x4){0.f, 0.f, 0.f, 0.f};
        s.oacc1[ns] = (f32x4){0.f, 0.f, 0.f, 0.f};
    }

    // K global register frags (named sets, static indexing only)
    half8 kbA[2][2], kbB[2][2];

    // ---- prologue: V(kt0) -> buf0, K(kt0) -> kbA ----
    loadK(s, kbA, kt0);
    loadV(s, kt0);
    writeV<0>(s);
    __syncthreads();

    // span (kt1-kt0) is always even -> clean 2-unroll, no tail
    for (int kt = kt0; kt < kt1; kt += 2) {
        stepAttn<0>(s, kt,     kbA, kbB);
        stepAttn<1>(s, kt + 1, kbB, kbA);
    }

    // ---- epilogue: reduce l across quads, store O (f16) and linear l ----
    float l0 = s.l0, l1 = s.l1;
    l0 += __shfl_xor(l0, 16, 64);
    l0 += __shfl_xor(l0, 32, 64);
    l1 += __shfl_xor(l1, 16, 64);
    l1 += __shfl_xor(l1, 32, 64);
    if (quad == 0) {
        Lp[(size_t)outblk * 128 + 16 * wid + l15]      = l0;
        Lp[(size_t)outblk * 128 + 64 + 16 * wid + l15] = l1;
    }
    const int qrow0 = 16 * wid + quad * 4;
#pragma unroll
    for (int j = 0; j < 4; ++j) {
        const float inv0 = 1.0f / __shfl(l0, quad * 4 + j, 64);
        const float inv1 = 1.0f / __shfl(l1, quad * 4 + j, 64);
        const size_t r0off = ((size_t)outblk * 128 + qrow0 + j) * 64 + l15;
        const size_t r1off = ((size_t)outblk * 128 + 64 + qrow0 + j) * 64 + l15;
#pragma unroll
        for (int ns = 0; ns < 4; ++ns) {
            Op[r0off + ns * 16] = (_Float16)(s.oacc0[ns][j] * inv0);
            Op[r1off + ns * 16] = (_Float16)(s.oacc1[ns][j] * inv1);
        }
    }
}

// ---------------- kernel 3: merge all (window, chunk) partials ------------
// Linear mix (matches the reference's alpha = denom/denom_sum): no log/exp,
// no max pass. Per group: 8 clamped-unrolled slots (cmax = j>>8 <= 7),
// inactive groups branch-skipped (masked lanes fetch nothing).
typedef _Float16 half8v __attribute__((ext_vector_type(8)));
__global__ __launch_bounds__(256) void mix_out(
        const _Float16* __restrict__ Op, const float* __restrict__ Lp,
        float* __restrict__ out) {
    int gid = blockIdx.x * 256 + threadIdx.x;   // [0, 4*8192*8)
    int f8 = gid & 7;
    int tpos = (gid >> 3) & (NSEQ - 1);
    int b = gid >> 16;

    float wsum = 0.f;
    float acc[8];
#pragma unroll
    for (int k = 0; k < 8; ++k) acc[k] = 0.f;

    // group 0: stride-1 window (always active)
    {
        int w = tpos >> 11, j = tpos & (M - 1);
        int QT = j >> 7, q = j & 127, k2 = QT >> 1;
        int cbase = (QT & 1) ? (k2 + 1) * (k2 + 1) : k2 * (k2 + 1);
        int bb = ((b * NW + w) * NBLK2 + cbase) * 128 + q;
        int cmax = j >> 8;
#pragma unroll
        for (int c = 0; c < 8; ++c) {
            int cc = (c <= cmax) ? c : cmax;
            int ix = bb + cc * 128;
            float li = Lp[ix];
            li = (c <= cmax) ? li : 0.f;
            half8v v = *(const half8v*)(Op + (size_t)ix * 64 + f8 * 8);
            wsum += li;
#pragma unroll
            for (int k = 0; k < 8; ++k) acc[k] += li * (float)v[k];
        }
    }
    // group 1: stride-2 window (active iff tpos even)
    if (!(tpos & 1)) {
        int w = 4 + (tpos >> 12), j = (tpos & 4095) >> 1;
        int QT = j >> 7, q = j & 127, k2 = QT >> 1;
        int cbase = (QT & 1) ? (k2 + 1) * (k2 + 1) : k2 * (k2 + 1);
        int bb = ((b * NW + w) * NBLK2 + cbase) * 128 + q;
        int cmax = j >> 8;
#pragma unroll
        for (int c = 0; c < 8; ++c) {
            int cc = (c <= cmax) ? c : cmax;
            int ix = bb + cc * 128;
            float li = Lp[ix];
            li = (c <= cmax) ? li : 0.f;
            half8v v = *(const half8v*)(Op + (size_t)ix * 64 + f8 * 8);
            wsum += li;
#pragma unroll
            for (int k = 0; k < 8; ++k) acc[k] += li * (float)v[k];
        }
    }
    // group 2: stride-4 window (active iff tpos % 4 == 0)
    if (!(tpos & 3)) {
        int j = tpos >> 2;
        int QT = j >> 7, q = j & 127, k2 = QT >> 1;
        int cbase = (QT & 1) ? (k2 + 1) * (k2 + 1) : k2 * (k2 + 1);
        int bb = ((b * NW + 6) * NBLK2 + cbase) * 128 + q;
        int cmax = j >> 8;
#pragma unroll
        for (int c = 0; c < 8; ++c) {
            int cc = (c <= cmax) ? c : cmax;
            int ix = bb + cc * 128;
            float li = Lp[ix];
            li = (c <= cmax) ? li : 0.f;
            half8v v = *(const half8v*)(Op + (size_t)ix * 64 + f8 * 8);
            wsum += li;
#pragma unroll
            for (int k = 0; k < 8; ++k) acc[k] += li * (float)v[k];
        }
    }

    float inv = 1.0f / wsum;
    size_t o = ((size_t)b * NSEQ + tpos) * 64 + f8 * 8;
    float4 r0 = make_float4(acc[0] * inv, acc[1] * inv, acc[2] * inv, acc[3] * inv);
    float4 r1 = make_float4(acc[4] * inv, acc[5] * inv, acc[6] * inv, acc[7] * inv);
    *(float4*)&out[o] = r0;
    *(float4*)&out[o + 4] = r1;
}

extern "C" void kernel_launch(void* const* d_in, const int* in_sizes, int n_in,
                              void* d_out, int out_size, void* d_ws, size_t ws_size,
                              hipStream_t stream) {
    const float* x  = (const float*)d_in[0];
    const float* Wq = (const float*)d_in[1];
    const float* Wk = (const float*)d_in[2];
    const float* Wv = (const float*)d_in[3];
    float* out = (float*)d_out;

    const size_t QN = (size_t)NB * NSEQ * CDIM;     // 2,097,152
    _Float16* Qg = (_Float16*)d_ws;
    _Float16* Kg = Qg + QN;
    _Float16* Vg = Kg + QN;
    _Float16* Op = Vg + QN;                         // [b][w][72][128][64] f16
    float* Lp   = (float*)(Op + (size_t)NB * NW * NBLK2 * 128 * 64);

    qkv_proj<<<NB * NSEQ / 128, 256, 0, stream>>>(x, Wq, Wk, Wv, Qg, Kg, Vg);
    attn<<<dim3(NBLK2, NW, NB), 256, 0, stream>>>(Qg, Kg, Vg, Op, Lp);
    mix_out<<<(NB * NSEQ * 8) / 256, 256, 0, stream>>>(Op, Lp, out);
}

// Round 8
// 195.879 us; speedup vs baseline: 1.0111x; 1.0111x over previous
//
#include <hip/hip_runtime.h>
#include <math.h>

#define NB   4
#define NSEQ 8192
#define CDIM 64
#define M    2048
#define NW   7
#define NBLK2 72     // 8-step kv-chunks per window: sum_QT ((QT>>1)+1) = 72

typedef _Float16 half8 __attribute__((ext_vector_type(8)));
typedef __fp16 fp16x2 __attribute__((ext_vector_type(2)));   // native cvt_pkrtz type
typedef float f32x4 __attribute__((ext_vector_type(4)));
typedef unsigned short u16x4 __attribute__((ext_vector_type(4)));

#if defined(__has_builtin) && __has_builtin(__builtin_amdgcn_exp2f)
#define EXP2(x) __builtin_amdgcn_exp2f(x)
#else
#define EXP2(x) __expf((x) * 0.69314718056f)
#endif

// Q pre-scale: 1/sqrt(64) * log2(e) folded into Wq's B-frags so attn uses raw exp2
#define QSCALE 0.1803368801111204f
// exp bias: p = exp2(s' - PBIAS) keeps P under f16 max; scales P and l by
// 2^-PBIAS uniformly -> ratios invariant in the linear mix.
#define PBIAS 4.0f

// attn LDS (10240 B total — K is GONE from LDS, V dbuf only):
//   [0,10240): Vt dbuf, 2 x 64 rows x 80B stride, pair-packed
//              pi: word u of lane-quad Q = (V[kv=4Q+u], V[kv=4Q+u+16]),
//              chunk-XOR h(d)=(d>>4)^(d&3)^((d>>2)&3); stride 80 spreads
//              the b32 staging writes over all 32 banks.
// K is loaded per-wave straight from global into registers (1-step prefetch,
// named kbA/kbB sets, 2-unrolled loop — spans are always even).
// !!! ALL STATE MUST BE PLAIN LOCALS (SSA) — R7 packed it into a struct
// passed by reference and the compiler allocated it in SCRATCH: VGPR=64,
// WRITE_SIZE 250MB (~190MB spill stores), attn 116us. Macros, not structs.
// LAUNCH BOUNDS: (256,4). DO NOT raise the 2nd arg — measured twice (prev
// session + R2): allocator squeezes below the live set and spills accs to
// scratch (FETCH +190MB, attn 50->117us). (256,4) caps alloc at 128 VGPR.
#define VT_STRIDE 80
#define VT_BUF  5120

__device__ __forceinline__ int win_base(int w) {
    return (w < 4) ? (w << 11) : ((w < 6) ? ((w - 4) << 12) : 0);
}
__device__ __forceinline__ int win_stride(int w) {
    return (w < 4) ? 1 : ((w < 6) ? 2 : 4);
}

// ---------------- kernel 1: QKV projection via MFMA, f16 outputs ----------
__global__ __launch_bounds__(256, 1) void qkv_proj(
        const float* __restrict__ x,
        const float* __restrict__ Wq, const float* __restrict__ Wk,
        const float* __restrict__ Wv,
        _Float16* __restrict__ Qg, _Float16* __restrict__ Kg,
        _Float16* __restrict__ Vg) {
    const int t = threadIdx.x;
    const int wid = t >> 6, lane = t & 63, l15 = lane & 15, quad = lane >> 4;

    // ---- one-time: W -> B-frags (f32 load, scale Q, cvt to f16) ----
    half8 wb[3][2][4];
#pragma unroll
    for (int m = 0; m < 3; ++m) {
        const float* Wm = (m == 0) ? Wq : ((m == 1) ? Wk : Wv);
        const float sc = (m == 0) ? QSCALE : 1.0f;
#pragma unroll
        for (int kh = 0; kh < 2; ++kh)
#pragma unroll
            for (int nt = 0; nt < 4; ++nt) {
                float f[8];
#pragma unroll
                for (int j = 0; j < 8; ++j)
                    f[j] = Wm[(kh * 32 + quad * 8 + j) * 64 + nt * 16 + l15] * sc;
                union { fp16x2 h[4]; half8 v; } u;
#pragma unroll
                for (int p = 0; p < 4; ++p)
                    u.h[p] = __builtin_amdgcn_cvt_pkrtz(f[2 * p], f[2 * p + 1]);
                wb[m][kh][nt] = u.v;
            }
    }

    const int rowbase = blockIdx.x * 128 + wid * 32;
#pragma unroll
    for (int mt = 0; mt < 2; ++mt) {
        const int r0 = rowbase + mt * 16;
        // A-frags: X rows (r0+l15), f32 -> f16
        half8 xa[2];
#pragma unroll
        for (int kh = 0; kh < 2; ++kh) {
            const float* xr = x + (size_t)(r0 + l15) * 64 + kh * 32 + quad * 8;
            const float4 a = *(const float4*)xr;
            const float4 b2 = *(const float4*)(xr + 4);
            union { fp16x2 h[4]; half8 v; } u;
            u.h[0] = __builtin_amdgcn_cvt_pkrtz(a.x, a.y);
            u.h[1] = __builtin_amdgcn_cvt_pkrtz(a.z, a.w);
            u.h[2] = __builtin_amdgcn_cvt_pkrtz(b2.x, b2.y);
            u.h[3] = __builtin_amdgcn_cvt_pkrtz(b2.z, b2.w);
            xa[kh] = u.v;
        }
#pragma unroll
        for (int m = 0; m < 3; ++m) {
            f32x4 acc[4];
#pragma unroll
            for (int nt = 0; nt < 4; ++nt) {
                acc[nt] = (f32x4){0.f, 0.f, 0.f, 0.f};
                acc[nt] = __builtin_amdgcn_mfma_f32_16x16x32_f16(xa[0], wb[m][0][nt], acc[nt], 0, 0, 0);
                acc[nt] = __builtin_amdgcn_mfma_f32_16x16x32_f16(xa[1], wb[m][1][nt], acc[nt], 0, 0, 0);
            }
            _Float16* outp = (m == 0) ? Qg : ((m == 1) ? Kg : Vg);
#pragma unroll
            for (int nt = 0; nt < 4; ++nt)
#pragma unroll
                for (int j = 0; j < 4; ++j)
                    outp[(size_t)(r0 + quad * 4 + j) * 64 + nt * 16 + l15] =
                        (_Float16)acc[nt][j];
        }
    }
}

// ---------------- kernel 2: flash attention, 128q tile x 8 k-steps --------
// R18 = R17 algorithm, R6 macro form (plain locals, no struct).
__global__ __launch_bounds__(256, 4) void attn(
        const _Float16* __restrict__ Qg, const _Float16* __restrict__ Kg,
        const _Float16* __restrict__ Vg,
        _Float16* __restrict__ Op, float* __restrict__ Lp) {
    __shared__ __align__(16) char smem[10240];

    // decode (QT, ci): idx ascending in QT; blockIdx reversed -> heavy first
    const int idx = (NBLK2 - 1) - (int)blockIdx.x;
    int QT = 0;
    // cum(QT) table: 0,1,2,4,6,9,12,16,20,25,30,36,42,49,56,64
    QT += (idx >= 1);  QT += (idx >= 2);  QT += (idx >= 4);  QT += (idx >= 6);
    QT += (idx >= 9);  QT += (idx >= 12); QT += (idx >= 16); QT += (idx >= 20);
    QT += (idx >= 25); QT += (idx >= 30); QT += (idx >= 36); QT += (idx >= 42);
    QT += (idx >= 49); QT += (idx >= 56); QT += (idx >= 64);
    const int k2 = QT >> 1;
    const int cb = (QT & 1) ? (k2 + 1) * (k2 + 1) : k2 * (k2 + 1);
    const int ci = idx - cb;
    const int w = blockIdx.y, b = blockIdx.z;
    const int base = win_base(w), stride = win_stride(w);
    const int outblk = (b * NW + w) * NBLK2 + cb + ci;
    const int kt0 = ci * 8;                  // 32-col steps
    const int ktmax = 4 * QT + 4;
    const int kt1 = (kt0 + 8 < ktmax) ? kt0 + 8 : ktmax;   // span always EVEN

    const _Float16* Qb = Qg + (size_t)b * NSEQ * 64;
    const _Float16* Kb = Kg + (size_t)b * NSEQ * 64;
    const _Float16* Vb = Vg + (size_t)b * NSEQ * 64;

    const int t = threadIdx.x;
    const int wid = t >> 6, lane = t & 63, l15 = lane & 15, quad = lane >> 4;

    // V staging: thread (c4 = cols 4c4.., kq = k-pair row)
    const int c4 = t & 15, kq = t >> 4;      // kq in 0..15
    const int vd0 = 4 * c4;

    // Q frags for both strips, load once; used as MFMA *B* operand
    const size_t qr0 = (size_t)(base + stride * (QT * 128 + 16 * wid + l15)) * 64;
    const size_t qr1 = (size_t)(base + stride * (QT * 128 + 64 + 16 * wid + l15)) * 64;
    const half8 qa00 = *(const half8*)(Qb + qr0 + quad * 8);
    const half8 qa01 = *(const half8*)(Qb + qr0 + 32 + quad * 8);
    const half8 qa10 = *(const half8*)(Qb + qr1 + quad * 8);
    const half8 qa11 = *(const half8*)(Qb + qr1 + 32 + quad * 8);

    f32x4 oacc0[4], oacc1[4];
    float l0 = 0.f, l1 = 0.f;                // per-lane partial row sums
#pragma unroll
    for (int ns = 0; ns < 4; ++ns) {
        oacc0[ns] = (f32x4){0.f, 0.f, 0.f, 0.f};
        oacc1[ns] = (f32x4){0.f, 0.f, 0.f, 0.f};
    }

    // K global register frags (named sets, static indexing only)
    half8 kbA[2][2], kbB[2][2];
    u16x4 pv0, pv1;

#define LOADK(kb, kt)                                                        \
    {                                                                        \
        _Pragma("unroll")                                                    \
        for (int ns = 0; ns < 2; ++ns) {                                     \
            const size_t kr =                                                \
                (size_t)(base + stride * ((kt) * 32 + ns * 16 + l15)) * 64;  \
            kb[ns][0] = *(const half8*)(Kb + kr + quad * 8);                 \
            kb[ns][1] = *(const half8*)(Kb + kr + 32 + quad * 8);            \
        }                                                                    \
    }

#define LOADV(kt)                                                            \
    {                                                                        \
        const size_t va =                                                    \
            (size_t)(base + stride * ((kt) * 32 + kq)) * 64 + vd0;           \
        pv0 = *(const u16x4*)(Vb + va);                                      \
        pv1 = *(const u16x4*)(Vb + va + (size_t)stride * 16 * 64);           \
    }

#define WRITEV(cur)                                                          \
    {                                                                        \
        char* Vn = smem + (cur) * VT_BUF;                                    \
        _Pragma("unroll")                                                    \
        for (int i = 0; i < 4; ++i) {                                        \
            int d = vd0 + i;                                                 \
            unsigned int pkw =                                               \
                (unsigned int)pv0[i] | ((unsigned int)pv1[i] << 16);         \
            int ch = ((kq >> 2) ^ (d >> 4) ^ (d & 3) ^ ((d >> 2) & 3)) & 3;  \
            *(unsigned int*)(Vn + d * VT_STRIDE + ch * 16 + (kq & 3) * 4) =  \
                pkw;                                                         \
        }                                                                    \
    }

    // ---- prologue: V(kt0) -> buf0, K(kt0) -> kbA ----
    LOADK(kbA, kt0);
    LOADV(kt0);
    WRITEV(0);
    __syncthreads();

#define STEP(kt, kbC, kbN, cur)                                              \
    {                                                                        \
        const bool pf = ((kt) + 1 < kt1);                                    \
        if (pf) {                                                            \
            LOADK(kbN, (kt) + 1);                                            \
            LOADV((kt) + 1);                                                 \
        }                                                                    \
        const char* Vd = smem + (cur) * VT_BUF;                              \
        half8 vb[4];                                                         \
        _Pragma("unroll")                                                    \
        for (int ns = 0; ns < 4; ++ns) {                                     \
            const int d = ns * 16 + l15;                                     \
            const int ch = (quad ^ (d >> 4) ^ (d & 3) ^ ((d >> 2) & 3)) & 3; \
            vb[ns] = *(const half8*)(Vd + d * VT_STRIDE + ch * 16);          \
        }                                                                    \
        f32x4 sa0[2], sa1[2];                                                \
        __builtin_amdgcn_s_setprio(1);                                       \
        _Pragma("unroll")                                                    \
        for (int ns = 0; ns < 2; ++ns) {                                     \
            f32x4 c0 = (f32x4){0.f, 0.f, 0.f, 0.f};                          \
            c0 = __builtin_amdgcn_mfma_f32_16x16x32_f16(kbC[ns][0], qa00, c0, 0, 0, 0); \
            c0 = __builtin_amdgcn_mfma_f32_16x16x32_f16(kbC[ns][1], qa01, c0, 0, 0, 0); \
            sa0[ns] = c0;                                                    \
            f32x4 c1 = (f32x4){0.f, 0.f, 0.f, 0.f};                          \
            c1 = __builtin_amdgcn_mfma_f32_16x16x32_f16(kbC[ns][0], qa10, c1, 0, 0, 0); \
            c1 = __builtin_amdgcn_mfma_f32_16x16x32_f16(kbC[ns][1], qa11, c1, 0, 0, 0); \
            sa1[ns] = c1;                                                    \
        }                                                                    \
        __builtin_amdgcn_s_setprio(0);                                       \
        if ((kt) >= 4 * QT) {                                                \
            const int q0 = QT * 128 + 16 * wid + l15 - (kt) * 32;            \
            const int kvb = quad * 4;                                        \
            _Pragma("unroll")                                                \
            for (int ns = 0; ns < 2; ++ns)                                   \
                _Pragma("unroll")                                            \
                for (int j = 0; j < 4; ++j) {                                \
                    if (kvb + ns * 16 + j > q0)      sa0[ns][j] = -1e30f;    \
                    if (kvb + ns * 16 + j > q0 + 64) sa1[ns][j] = -1e30f;    \
                }                                                            \
        }                                                                    \
        {                                                                    \
            union { fp16x2 h[4]; half8 v; } pu;                              \
            _Pragma("unroll")                                                \
            for (int u = 0; u < 4; ++u) {                                    \
                float pA = EXP2(sa0[0][u] - PBIAS);                          \
                float pB = EXP2(sa0[1][u] - PBIAS);                          \
                l0 += pA + pB;                                               \
                pu.h[u] = __builtin_amdgcn_cvt_pkrtz(pA, pB);                \
            }                                                                \
            __builtin_amdgcn_s_setprio(1);                                   \
            _Pragma("unroll")                                                \
            for (int ns = 0; ns < 4; ++ns)                                   \
                oacc0[ns] = __builtin_amdgcn_mfma_f32_16x16x32_f16(pu.v, vb[ns], oacc0[ns], 0, 0, 0); \
            __builtin_amdgcn_s_setprio(0);                                   \
        }                                                                    \
        {                                                                    \
            union { fp16x2 h[4]; half8 v; } pu;                              \
            _Pragma("unroll")                                                \
            for (int u = 0; u < 4; ++u) {                                    \
                float pA = EXP2(sa1[0][u] - PBIAS);                          \
                float pB = EXP2(sa1[1][u] - PBIAS);                          \
                l1 += pA + pB;                                               \
                pu.h[u] = __builtin_amdgcn_cvt_pkrtz(pA, pB);                \
            }                                                                \
            __builtin_amdgcn_s_setprio(1);                                   \
            _Pragma("unroll")                                                \
            for (int ns = 0; ns < 4; ++ns)                                   \
                oacc1[ns] = __builtin_amdgcn_mfma_f32_16x16x32_f16(pu.v, vb[ns], oacc1[ns], 0, 0, 0); \
            __builtin_amdgcn_s_setprio(0);                                   \
        }                                                                    \
        if (pf) WRITEV((cur) ^ 1);                                           \
        __syncthreads();                                                     \
    }

    // span (kt1-kt0) is always even -> clean 2-unroll, no tail
    for (int kt = kt0; kt < kt1; kt += 2) {
        STEP(kt,     kbA, kbB, 0);
        STEP(kt + 1, kbB, kbA, 1);
    }

    // ---- epilogue: reduce l across quads, store O (f16) and linear l ----
    l0 += __shfl_xor(l0, 16, 64);
    l0 += __shfl_xor(l0, 32, 64);
    l1 += __shfl_xor(l1, 16, 64);
    l1 += __shfl_xor(l1, 32, 64);
    if (quad == 0) {
        Lp[(size_t)outblk * 128 + 16 * wid + l15]      = l0;
        Lp[(size_t)outblk * 128 + 64 + 16 * wid + l15] = l1;
    }
    const int qrow0 = 16 * wid + quad * 4;
#pragma unroll
    for (int j = 0; j < 4; ++j) {
        const float inv0 = 1.0f / __shfl(l0, quad * 4 + j, 64);
        const float inv1 = 1.0f / __shfl(l1, quad * 4 + j, 64);
        const size_t r0off = ((size_t)outblk * 128 + qrow0 + j) * 64 + l15;
        const size_t r1off = ((size_t)outblk * 128 + 64 + qrow0 + j) * 64 + l15;
#pragma unroll
        for (int ns = 0; ns < 4; ++ns) {
            Op[r0off + ns * 16] = (_Float16)(oacc0[ns][j] * inv0);
            Op[r1off + ns * 16] = (_Float16)(oacc1[ns][j] * inv1);
        }
    }
}

// ---------------- kernel 3: merge all (window, chunk) partials ------------
// Linear mix (matches the reference's alpha = denom/denom_sum): no log/exp,
// no max pass. Per group: 8 clamped-unrolled slots (cmax = j>>8 <= 7),
// inactive groups branch-skipped (masked lanes fetch nothing).
typedef _Float16 half8v __attribute__((ext_vector_type(8)));
__global__ __launch_bounds__(256) void mix_out(
        const _Float16* __restrict__ Op, const float* __restrict__ Lp,
        float* __restrict__ out) {
    int gid = blockIdx.x * 256 + threadIdx.x;   // [0, 4*8192*8)
    int f8 = gid & 7;
    int tpos = (gid >> 3) & (NSEQ - 1);
    int b = gid >> 16;

    float wsum = 0.f;
    float acc[8];
#pragma unroll
    for (int k = 0; k < 8; ++k) acc[k] = 0.f;

    // group 0: stride-1 window (always active)
    {
        int w = tpos >> 11, j = tpos & (M - 1);
        int QT = j >> 7, q = j & 127, k2 = QT >> 1;
        int cbase = (QT & 1) ? (k2 + 1) * (k2 + 1) : k2 * (k2 + 1);
        int bb = ((b * NW + w) * NBLK2 + cbase) * 128 + q;
        int cmax = j >> 8;
#pragma unroll
        for (int c = 0; c < 8; ++c) {
            int cc = (c <= cmax) ? c : cmax;
            int ix = bb + cc * 128;
            float li = Lp[ix];
            li = (c <= cmax) ? li : 0.f;
            half8v v = *(const half8v*)(Op + (size_t)ix * 64 + f8 * 8);
            wsum += li;
#pragma unroll
            for (int k = 0; k < 8; ++k) acc[k] += li * (float)v[k];
        }
    }
    // group 1: stride-2 window (active iff tpos even)
    if (!(tpos & 1)) {
        int w = 4 + (tpos >> 12), j = (tpos & 4095) >> 1;
        int QT = j >> 7, q = j & 127, k2 = QT >> 1;
        int cbase = (QT & 1) ? (k2 + 1) * (k2 + 1) : k2 * (k2 + 1);
        int bb = ((b * NW + w) * NBLK2 + cbase) * 128 + q;
        int cmax = j >> 8;
#pragma unroll
        for (int c = 0; c < 8; ++c) {
            int cc = (c <= cmax) ? c : cmax;
            int ix = bb + cc * 128;
            float li = Lp[ix];
            li = (c <= cmax) ? li : 0.f;
            half8v v = *(const half8v*)(Op + (size_t)ix * 64 + f8 * 8);
            wsum += li;
#pragma unroll
            for (int k = 0; k < 8; ++k) acc[k] += li * (float)v[k];
        }
    }
    // group 2: stride-4 window (active iff tpos % 4 == 0)
    if (!(tpos & 3)) {
        int j = tpos >> 2;
        int QT = j >> 7, q = j & 127, k2 = QT >> 1;
        int cbase = (QT & 1) ? (k2 + 1) * (k2 + 1) : k2 * (k2 + 1);
        int bb = ((b * NW + 6) * NBLK2 + cbase) * 128 + q;
        int cmax = j >> 8;
#pragma unroll
        for (int c = 0; c < 8; ++c) {
            int cc = (c <= cmax) ? c : cmax;
            int ix = bb + cc * 128;
            float li = Lp[ix];
            li = (c <= cmax) ? li : 0.f;
            half8v v = *(const half8v*)(Op + (size_t)ix * 64 + f8 * 8);
            wsum += li;
#pragma unroll
            for (int k = 0; k < 8; ++k) acc[k] += li * (float)v[k];
        }
    }

    float inv = 1.0f / wsum;
    size_t o = ((size_t)b * NSEQ + tpos) * 64 + f8 * 8;
    float4 r0 = make_float4(acc[0] * inv, acc[1] * inv, acc[2] * inv, acc[3] * inv);
    float4 r1 = make_float4(acc[4] * inv, acc[5] * inv, acc[6] * inv, acc[7] * inv);
    *(float4*)&out[o] = r0;
    *(float4*)&out[o + 4] = r1;
}

extern "C" void kernel_launch(void* const* d_in, const int* in_sizes, int n_in,
                              void* d_out, int out_size, void* d_ws, size_t ws_size,
                              hipStream_t stream) {
    const float* x  = (const float*)d_in[0];
    const float* Wq = (const float*)d_in[1];
    const float* Wk = (const float*)d_in[2];
    const float* Wv = (const float*)d_in[3];
    float* out = (float*)d_out;

    const size_t QN = (size_t)NB * NSEQ * CDIM;     // 2,097,152
    _Float16* Qg = (_Float16*)d_ws;
    _Float16* Kg = Qg + QN;
    _Float16* Vg = Kg + QN;
    _Float16* Op = Vg + QN;                         // [b][w][72][128][64] f16
    float* Lp   = (float*)(Op + (size_t)NB * NW * NBLK2 * 128 * 64);

    qkv_proj<<<NB * NSEQ / 128, 256, 0, stream>>>(x, Wq, Wk, Wv, Qg, Kg, Vg);
    attn<<<dim3(NBLK2, NW, NB), 256, 0, stream>>>(Qg, Kg, Vg, Op, Lp);
    mix_out<<<(NB * NSEQ * 8) / 256, 256, 0, stream>>>(Op, Lp, out);
}

// Round 9
// 126.042 us; speedup vs baseline: 1.5713x; 1.5541x over previous
//
#include <hip/hip_runtime.h>
#include <math.h>

#define NB   4
#define NSEQ 8192
#define CDIM 64
#define M    2048
#define NW   7
#define NBLK2 72     // 8-step kv-chunks per window: sum_QT ((QT>>1)+1) = 72

typedef _Float16 half8 __attribute__((ext_vector_type(8)));
typedef __fp16 fp16x2 __attribute__((ext_vector_type(2)));   // native cvt_pkrtz type
typedef float f32x4 __attribute__((ext_vector_type(4)));
typedef unsigned short u16x4 __attribute__((ext_vector_type(4)));

#if defined(__has_builtin) && __has_builtin(__builtin_amdgcn_exp2f)
#define EXP2(x) __builtin_amdgcn_exp2f(x)
#else
#define EXP2(x) __expf((x) * 0.69314718056f)
#endif

// Q pre-scale: 1/sqrt(64) * log2(e) folded into Wq's B-frags so attn uses raw exp2
#define QSCALE 0.1803368801111204f
// exp bias: p = exp2(s' - PBIAS) keeps P under f16 max; scales P and l by
// 2^-PBIAS uniformly -> ratios invariant in the linear mix.
#define PBIAS 4.0f

// attn LDS (10240 B — V dbuf only):
//   [0,10240): Vt dbuf, 2 x 64 rows x 80B stride, pair-packed
//              pi: word u of lane-quad Q = (V[kv=4Q+u], V[kv=4Q+u+16]),
//              chunk-XOR h(d)=(d>>4)^(d&3)^((d>>2)&3); stride 80 spreads
//              the b32 staging writes over all 32 banks.
// K: loaded from global into a SINGLE register set kb[2][2] at the top of
// each step (frag = K[kt*32+ns*16+l15][quad*8+32h..+8], coalesced rows,
// 4 waves share 2KB -> L1/L2). K loads are issued BEFORE the V prefetch so
// the QK^T's counted vmcnt waits only on K.
// !!! R7/R8 lesson: a SECOND K prefetch set (kbA+kbB) pushed peak live VGPRs
// to ~135 > the (256,4) cap of 128 -> catastrophic scratch spill (WRITE
// +216MB, attn 114us). Struct-vs-macro made NO difference (identical
// counters) — the liveness was the cause. Single set fits (~110-115 peak).
// LAUNCH BOUNDS: (256,4). DO NOT raise the 2nd arg (R2: spills at (256,5)).
#define VT_STRIDE 80
#define VT_BUF  5120

__device__ __forceinline__ int win_base(int w) {
    return (w < 4) ? (w << 11) : ((w < 6) ? ((w - 4) << 12) : 0);
}
__device__ __forceinline__ int win_stride(int w) {
    return (w < 4) ? 1 : ((w < 6) ? 2 : 4);
}

// ---------------- kernel 1: QKV projection via MFMA, f16 outputs ----------
__global__ __launch_bounds__(256, 1) void qkv_proj(
        const float* __restrict__ x,
        const float* __restrict__ Wq, const float* __restrict__ Wk,
        const float* __restrict__ Wv,
        _Float16* __restrict__ Qg, _Float16* __restrict__ Kg,
        _Float16* __restrict__ Vg) {
    const int t = threadIdx.x;
    const int wid = t >> 6, lane = t & 63, l15 = lane & 15, quad = lane >> 4;

    // ---- one-time: W -> B-frags (f32 load, scale Q, cvt to f16) ----
    half8 wb[3][2][4];
#pragma unroll
    for (int m = 0; m < 3; ++m) {
        const float* Wm = (m == 0) ? Wq : ((m == 1) ? Wk : Wv);
        const float sc = (m == 0) ? QSCALE : 1.0f;
#pragma unroll
        for (int kh = 0; kh < 2; ++kh)
#pragma unroll
            for (int nt = 0; nt < 4; ++nt) {
                float f[8];
#pragma unroll
                for (int j = 0; j < 8; ++j)
                    f[j] = Wm[(kh * 32 + quad * 8 + j) * 64 + nt * 16 + l15] * sc;
                union { fp16x2 h[4]; half8 v; } u;
#pragma unroll
                for (int p = 0; p < 4; ++p)
                    u.h[p] = __builtin_amdgcn_cvt_pkrtz(f[2 * p], f[2 * p + 1]);
                wb[m][kh][nt] = u.v;
            }
    }

    const int rowbase = blockIdx.x * 128 + wid * 32;
#pragma unroll
    for (int mt = 0; mt < 2; ++mt) {
        const int r0 = rowbase + mt * 16;
        // A-frags: X rows (r0+l15), f32 -> f16
        half8 xa[2];
#pragma unroll
        for (int kh = 0; kh < 2; ++kh) {
            const float* xr = x + (size_t)(r0 + l15) * 64 + kh * 32 + quad * 8;
            const float4 a = *(const float4*)xr;
            const float4 b2 = *(const float4*)(xr + 4);
            union { fp16x2 h[4]; half8 v; } u;
            u.h[0] = __builtin_amdgcn_cvt_pkrtz(a.x, a.y);
            u.h[1] = __builtin_amdgcn_cvt_pkrtz(a.z, a.w);
            u.h[2] = __builtin_amdgcn_cvt_pkrtz(b2.x, b2.y);
            u.h[3] = __builtin_amdgcn_cvt_pkrtz(b2.z, b2.w);
            xa[kh] = u.v;
        }
#pragma unroll
        for (int m = 0; m < 3; ++m) {
            f32x4 acc[4];
#pragma unroll
            for (int nt = 0; nt < 4; ++nt) {
                acc[nt] = (f32x4){0.f, 0.f, 0.f, 0.f};
                acc[nt] = __builtin_amdgcn_mfma_f32_16x16x32_f16(xa[0], wb[m][0][nt], acc[nt], 0, 0, 0);
                acc[nt] = __builtin_amdgcn_mfma_f32_16x16x32_f16(xa[1], wb[m][1][nt], acc[nt], 0, 0, 0);
            }
            _Float16* outp = (m == 0) ? Qg : ((m == 1) ? Kg : Vg);
#pragma unroll
            for (int nt = 0; nt < 4; ++nt)
#pragma unroll
                for (int j = 0; j < 4; ++j)
                    outp[(size_t)(r0 + quad * 4 + j) * 64 + nt * 16 + l15] =
                        (_Float16)acc[nt][j];
        }
    }
}

// ---------------- kernel 2: flash attention, 128q tile x 8 k-steps --------
// R19 = R5 structure + single-set K-from-global (no K prefetch, no K LDS).
__global__ __launch_bounds__(256, 4) void attn(
        const _Float16* __restrict__ Qg, const _Float16* __restrict__ Kg,
        const _Float16* __restrict__ Vg,
        _Float16* __restrict__ Op, float* __restrict__ Lp) {
    __shared__ __align__(16) char smem[10240];

    // decode (QT, ci): idx ascending in QT; blockIdx reversed -> heavy first
    const int idx = (NBLK2 - 1) - (int)blockIdx.x;
    int QT = 0;
    // cum(QT) table: 0,1,2,4,6,9,12,16,20,25,30,36,42,49,56,64
    QT += (idx >= 1);  QT += (idx >= 2);  QT += (idx >= 4);  QT += (idx >= 6);
    QT += (idx >= 9);  QT += (idx >= 12); QT += (idx >= 16); QT += (idx >= 20);
    QT += (idx >= 25); QT += (idx >= 30); QT += (idx >= 36); QT += (idx >= 42);
    QT += (idx >= 49); QT += (idx >= 56); QT += (idx >= 64);
    const int k2 = QT >> 1;
    const int cb = (QT & 1) ? (k2 + 1) * (k2 + 1) : k2 * (k2 + 1);
    const int ci = idx - cb;
    const int w = blockIdx.y, b = blockIdx.z;
    const int base = win_base(w), stride = win_stride(w);
    const int outblk = (b * NW + w) * NBLK2 + cb + ci;
    const int kt0 = ci * 8;                  // 32-col steps
    const int ktmax = 4 * QT + 4;
    const int kt1 = (kt0 + 8 < ktmax) ? kt0 + 8 : ktmax;

    const _Float16* Qb = Qg + (size_t)b * NSEQ * 64;
    const _Float16* Kb = Kg + (size_t)b * NSEQ * 64;
    const _Float16* Vb = Vg + (size_t)b * NSEQ * 64;

    const int t = threadIdx.x;
    const int wid = t >> 6, lane = t & 63, l15 = lane & 15, quad = lane >> 4;

    // V staging: thread (c4 = cols 4c4.., kq = k-pair row)
    const int c4 = t & 15, kq = t >> 4;      // kq in 0..15
    const int vd0 = 4 * c4;

    // Q frags for both strips, load once; used as MFMA *B* operand
    const size_t qr0 = (size_t)(base + stride * (QT * 128 + 16 * wid + l15)) * 64;
    const size_t qr1 = (size_t)(base + stride * (QT * 128 + 64 + 16 * wid + l15)) * 64;
    const half8 qa00 = *(const half8*)(Qb + qr0 + quad * 8);
    const half8 qa01 = *(const half8*)(Qb + qr0 + 32 + quad * 8);
    const half8 qa10 = *(const half8*)(Qb + qr1 + quad * 8);
    const half8 qa11 = *(const half8*)(Qb + qr1 + 32 + quad * 8);

    f32x4 oacc0[4], oacc1[4];
    float l0 = 0.f, l1 = 0.f;                // per-lane partial row sums
#pragma unroll
    for (int ns = 0; ns < 4; ++ns) {
        oacc0[ns] = (f32x4){0.f, 0.f, 0.f, 0.f};
        oacc1[ns] = (f32x4){0.f, 0.f, 0.f, 0.f};
    }

    u16x4 pv0, pv1;

    // ---- prologue: stage V(kt0) into buffer 0 ----
    {
        const size_t va = (size_t)(base + stride * (kt0 * 32 + kq)) * 64 + vd0;
        pv0 = *(const u16x4*)(Vb + va);
        pv1 = *(const u16x4*)(Vb + va + (size_t)stride * 16 * 64);
        char* Vd = smem;
#pragma unroll
        for (int i = 0; i < 4; ++i) {
            int d = vd0 + i;
            unsigned int pkw = (unsigned int)pv0[i] | ((unsigned int)pv1[i] << 16);
            int ch = ((kq >> 2) ^ (d >> 4) ^ (d & 3) ^ ((d >> 2) & 3)) & 3;
            *(unsigned int*)(Vd + d * VT_STRIDE + ch * 16 + (kq & 3) * 4) = pkw;
        }
    }

    int cur = 0;
    for (int kt = kt0; kt < kt1; ++kt) {
        __syncthreads();   // buf[cur] visible; all reads of buf[cur^1] done

        // ---- K for THIS step: global -> regs, issued FIRST ----
        half8 kb[2][2];
#pragma unroll
        for (int ns = 0; ns < 2; ++ns) {
            const size_t kr =
                (size_t)(base + stride * (kt * 32 + ns * 16 + l15)) * 64;
            kb[ns][0] = *(const half8*)(Kb + kr + quad * 8);
            kb[ns][1] = *(const half8*)(Kb + kr + 32 + quad * 8);
        }

        const bool pf = (kt + 1 < kt1);
        if (pf) {   // V prefetch for next step (issued after K; consumed late)
            const size_t va = (size_t)(base + stride * ((kt + 1) * 32 + kq)) * 64 + vd0;
            pv0 = *(const u16x4*)(Vb + va);
            pv1 = *(const u16x4*)(Vb + va + (size_t)stride * 16 * 64);
        }

        const char* Vd = smem + cur * VT_BUF;

        // ---- Vt B-frags (ds_read, overlaps K vmcnt wait) ----
        half8 vb[4];
#pragma unroll
        for (int ns = 0; ns < 4; ++ns) {
            const int d = ns * 16 + l15;
            const int ch = (quad ^ (d >> 4) ^ (d & 3) ^ ((d >> 2) & 3)) & 3;
            vb[ns] = *(const half8*)(Vd + d * VT_STRIDE + ch * 16);
        }

        // ---- swapped QK^T: S^T[kv_local=ns*16+quad*4+j][q=l15] ----
        f32x4 sa0[2], sa1[2];
        __builtin_amdgcn_s_setprio(1);
#pragma unroll
        for (int ns = 0; ns < 2; ++ns) {
            f32x4 c0 = (f32x4){0.f, 0.f, 0.f, 0.f};
            c0 = __builtin_amdgcn_mfma_f32_16x16x32_f16(kb[ns][0], qa00, c0, 0, 0, 0);
            c0 = __builtin_amdgcn_mfma_f32_16x16x32_f16(kb[ns][1], qa01, c0, 0, 0, 0);
            sa0[ns] = c0;
            f32x4 c1 = (f32x4){0.f, 0.f, 0.f, 0.f};
            c1 = __builtin_amdgcn_mfma_f32_16x16x32_f16(kb[ns][0], qa10, c1, 0, 0, 0);
            c1 = __builtin_amdgcn_mfma_f32_16x16x32_f16(kb[ns][1], qa11, c1, 0, 0, 0);
            sa1[ns] = c1;
        }
        __builtin_amdgcn_s_setprio(0);
        if (kt >= 4 * QT) {   // causal region (last 4 steps of the tile)
            const int q0 = QT * 128 + 16 * wid + l15 - kt * 32;  // vs kv_local
            const int kvb = quad * 4;
#pragma unroll
            for (int ns = 0; ns < 2; ++ns)
#pragma unroll
                for (int j = 0; j < 4; ++j) {
                    if (kvb + ns * 16 + j > q0)      sa0[ns][j] = -1e30f;
                    if (kvb + ns * 16 + j > q0 + 64) sa1[ns][j] = -1e30f;
                }
        }

        // ---- strip0: exp2 + in-register pack -> PV (NO LDS round-trip) ----
        {
            union { fp16x2 h[4]; half8 v; } pu;
#pragma unroll
            for (int u = 0; u < 4; ++u) {
                float pA = EXP2(sa0[0][u] - PBIAS);   // kv = 4*quad+u
                float pB = EXP2(sa0[1][u] - PBIAS);   // kv = 4*quad+u+16
                l0 += pA + pB;
                pu.h[u] = __builtin_amdgcn_cvt_pkrtz(pA, pB);
            }
            __builtin_amdgcn_s_setprio(1);
#pragma unroll
            for (int ns = 0; ns < 4; ++ns)
                oacc0[ns] = __builtin_amdgcn_mfma_f32_16x16x32_f16(pu.v, vb[ns], oacc0[ns], 0, 0, 0);
            __builtin_amdgcn_s_setprio(0);
        }
        // ---- strip1 ----
        {
            union { fp16x2 h[4]; half8 v; } pu;
#pragma unroll
            for (int u = 0; u < 4; ++u) {
                float pA = EXP2(sa1[0][u] - PBIAS);
                float pB = EXP2(sa1[1][u] - PBIAS);
                l1 += pA + pB;
                pu.h[u] = __builtin_amdgcn_cvt_pkrtz(pA, pB);
            }
            __builtin_amdgcn_s_setprio(1);
#pragma unroll
            for (int ns = 0; ns < 4; ++ns)
                oacc1[ns] = __builtin_amdgcn_mfma_f32_16x16x32_f16(pu.v, vb[ns], oacc1[ns], 0, 0, 0);
            __builtin_amdgcn_s_setprio(0);
        }

        // ---- write prefetched V into the other buffer ----
        if (pf) {
            char* Vn = smem + (cur ^ 1) * VT_BUF;
#pragma unroll
            for (int i = 0; i < 4; ++i) {
                int d = vd0 + i;
                unsigned int pkw = (unsigned int)pv0[i] | ((unsigned int)pv1[i] << 16);
                int ch = ((kq >> 2) ^ (d >> 4) ^ (d & 3) ^ ((d >> 2) & 3)) & 3;
                *(unsigned int*)(Vn + d * VT_STRIDE + ch * 16 + (kq & 3) * 4) = pkw;
            }
        }
        cur ^= 1;
    }

    // ---- epilogue: reduce l across quads, store O (f16) and linear l ----
    l0 += __shfl_xor(l0, 16, 64);
    l0 += __shfl_xor(l0, 32, 64);
    l1 += __shfl_xor(l1, 16, 64);
    l1 += __shfl_xor(l1, 32, 64);
    if (quad == 0) {
        Lp[(size_t)outblk * 128 + 16 * wid + l15]      = l0;
        Lp[(size_t)outblk * 128 + 64 + 16 * wid + l15] = l1;
    }
    const int qrow0 = 16 * wid + quad * 4;
#pragma unroll
    for (int j = 0; j < 4; ++j) {
        const float inv0 = 1.0f / __shfl(l0, quad * 4 + j, 64);
        const float inv1 = 1.0f / __shfl(l1, quad * 4 + j, 64);
        const size_t r0off = ((size_t)outblk * 128 + qrow0 + j) * 64 + l15;
        const size_t r1off = ((size_t)outblk * 128 + 64 + qrow0 + j) * 64 + l15;
#pragma unroll
        for (int ns = 0; ns < 4; ++ns) {
            Op[r0off + ns * 16] = (_Float16)(oacc0[ns][j] * inv0);
            Op[r1off + ns * 16] = (_Float16)(oacc1[ns][j] * inv1);
        }
    }
}

// ---------------- kernel 3: merge all (window, chunk) partials ------------
// Linear mix (matches the reference's alpha = denom/denom_sum): no log/exp,
// no max pass. Per group: 8 clamped-unrolled slots (cmax = j>>8 <= 7),
// inactive groups branch-skipped (masked lanes fetch nothing).
typedef _Float16 half8v __attribute__((ext_vector_type(8)));
__global__ __launch_bounds__(256) void mix_out(
        const _Float16* __restrict__ Op, const float* __restrict__ Lp,
        float* __restrict__ out) {
    int gid = blockIdx.x * 256 + threadIdx.x;   // [0, 4*8192*8)
    int f8 = gid & 7;
    int tpos = (gid >> 3) & (NSEQ - 1);
    int b = gid >> 16;

    float wsum = 0.f;
    float acc[8];
#pragma unroll
    for (int k = 0; k < 8; ++k) acc[k] = 0.f;

    // group 0: stride-1 window (always active)
    {
        int w = tpos >> 11, j = tpos & (M - 1);
        int QT = j >> 7, q = j & 127, k2 = QT >> 1;
        int cbase = (QT & 1) ? (k2 + 1) * (k2 + 1) : k2 * (k2 + 1);
        int bb = ((b * NW + w) * NBLK2 + cbase) * 128 + q;
        int cmax = j >> 8;
#pragma unroll
        for (int c = 0; c < 8; ++c) {
            int cc = (c <= cmax) ? c : cmax;
            int ix = bb + cc * 128;
            float li = Lp[ix];
            li = (c <= cmax) ? li : 0.f;
            half8v v = *(const half8v*)(Op + (size_t)ix * 64 + f8 * 8);
            wsum += li;
#pragma unroll
            for (int k = 0; k < 8; ++k) acc[k] += li * (float)v[k];
        }
    }
    // group 1: stride-2 window (active iff tpos even)
    if (!(tpos & 1)) {
        int w = 4 + (tpos >> 12), j = (tpos & 4095) >> 1;
        int QT = j >> 7, q = j & 127, k2 = QT >> 1;
        int cbase = (QT & 1) ? (k2 + 1) * (k2 + 1) : k2 * (k2 + 1);
        int bb = ((b * NW + w) * NBLK2 + cbase) * 128 + q;
        int cmax = j >> 8;
#pragma unroll
        for (int c = 0; c < 8; ++c) {
            int cc = (c <= cmax) ? c : cmax;
            int ix = bb + cc * 128;
            float li = Lp[ix];
            li = (c <= cmax) ? li : 0.f;
            half8v v = *(const half8v*)(Op + (size_t)ix * 64 + f8 * 8);
            wsum += li;
#pragma unroll
            for (int k = 0; k < 8; ++k) acc[k] += li * (float)v[k];
        }
    }
    // group 2: stride-4 window (active iff tpos % 4 == 0)
    if (!(tpos & 3)) {
        int j = tpos >> 2;
        int QT = j >> 7, q = j & 127, k2 = QT >> 1;
        int cbase = (QT & 1) ? (k2 + 1) * (k2 + 1) : k2 * (k2 + 1);
        int bb = ((b * NW + 6) * NBLK2 + cbase) * 128 + q;
        int cmax = j >> 8;
#pragma unroll
        for (int c = 0; c < 8; ++c) {
            int cc = (c <= cmax) ? c : cmax;
            int ix = bb + cc * 128;
            float li = Lp[ix];
            li = (c <= cmax) ? li : 0.f;
            half8v v = *(const half8v*)(Op + (size_t)ix * 64 + f8 * 8);
            wsum += li;
#pragma unroll
            for (int k = 0; k < 8; ++k) acc[k] += li * (float)v[k];
        }
    }

    float inv = 1.0f / wsum;
    size_t o = ((size_t)b * NSEQ + tpos) * 64 + f8 * 8;
    float4 r0 = make_float4(acc[0] * inv, acc[1] * inv, acc[2] * inv, acc[3] * inv);
    float4 r1 = make_float4(acc[4] * inv, acc[5] * inv, acc[6] * inv, acc[7] * inv);
    *(float4*)&out[o] = r0;
    *(float4*)&out[o + 4] = r1;
}

extern "C" void kernel_launch(void* const* d_in, const int* in_sizes, int n_in,
                              void* d_out, int out_size, void* d_ws, size_t ws_size,
                              hipStream_t stream) {
    const float* x  = (const float*)d_in[0];
    const float* Wq = (const float*)d_in[1];
    const float* Wk = (const float*)d_in[2];
    const float* Wv = (const float*)d_in[3];
    float* out = (float*)d_out;

    const size_t QN = (size_t)NB * NSEQ * CDIM;     // 2,097,152
    _Float16* Qg = (_Float16*)d_ws;
    _Float16* Kg = Qg + QN;
    _Float16* Vg = Kg + QN;
    _Float16* Op = Vg + QN;                         // [b][w][72][128][64] f16
    float* Lp   = (float*)(Op + (size_t)NB * NW * NBLK2 * 128 * 64);

    qkv_proj<<<NB * NSEQ / 128, 256, 0, stream>>>(x, Wq, Wk, Wv, Qg, Kg, Vg);
    attn<<<dim3(NBLK2, NW, NB), 256, 0, stream>>>(Qg, Kg, Vg, Op, Lp);
    mix_out<<<(NB * NSEQ * 8) / 256, 256, 0, stream>>>(Op, Lp, out);
}

// Round 10
// 119.910 us; speedup vs baseline: 1.6517x; 1.0511x over previous
//
#include <hip/hip_runtime.h>
#include <math.h>

#define NB   4
#define NSEQ 8192
#define CDIM 64
#define M    2048
#define NW   7
#define NBLK2 72     // 8-step kv-chunks per window: sum_QT ((QT>>1)+1) = 72

typedef _Float16 half8 __attribute__((ext_vector_type(8)));
typedef __fp16 fp16x2 __attribute__((ext_vector_type(2)));   // native cvt_pkrtz type
typedef float f32x4 __attribute__((ext_vector_type(4)));
typedef unsigned short u16x4 __attribute__((ext_vector_type(4)));

#if defined(__has_builtin) && __has_builtin(__builtin_amdgcn_exp2f)
#define EXP2(x) __builtin_amdgcn_exp2f(x)
#else
#define EXP2(x) __expf((x) * 0.69314718056f)
#endif

// Q pre-scale: 1/sqrt(64) * log2(e) folded into Wq's B-frags so attn uses raw exp2
#define QSCALE 0.1803368801111204f
// exp bias: p = exp2(s' - PBIAS) keeps P under f16 max; scales P and l by
// 2^-PBIAS uniformly -> ratios invariant in the linear mix.
#define PBIAS 4.0f

// attn LDS (36864 B): 4-deep buffers, TWO kv-steps per barrier.
//   [0,16384):      K, 4 bufs x (32 rows x 128B), XOR swizzle (conflict-free b128)
//   [16384,36864):  Vt, 4 bufs x (64 rows x 80B), pair-packed
//                   pi: word u of lane-quad Q = (V[kv=4Q+u], V[kv=4Q+u+16]),
//                   chunk-XOR h(d)=(d>>4)^(d&3)^((d>>2)&3); stride 80 spreads
//                   the b32 staging writes over all 32 banks.
// Buffers form 2 PAIRS; interval i computes pair i%2 (2 steps) and writes the
// prefetched next 2 steps into the other pair. 1 barrier per 2 steps: halves
// the per-barrier vmcnt(0) drains (R9 back-solve: ~2-3k cy/step >> ~700 cy
// compute chain -> drain-dominated). Race-free: a pair's writers are separated
// from its previous readers by the interval-top barrier (same as R5's dbuf,
// one pair deeper). Spans are {4,8} so the prologue's 2-step stage is safe.
// Prefetch regs: ONE 12-reg set reused (kt+2 then kt+3) — R8's double set
// (+16 live) blew the 128-VGPR cap and spilled 216MB. Keep it single.
// LAUNCH BOUNDS: (256,4). DO NOT raise the 2nd arg (R2: spills at (256,5)).
#define K_OFF   0
#define K_BUF   4096
#define VT_OFF  16384
#define VT_STRIDE 80
#define VT_BUF  5120

__device__ __forceinline__ int win_base(int w) {
    return (w < 4) ? (w << 11) : ((w < 6) ? ((w - 4) << 12) : 0);
}
__device__ __forceinline__ int win_stride(int w) {
    return (w < 4) ? 1 : ((w < 6) ? 2 : 4);
}

// ---------------- kernel 1: QKV projection via MFMA, f16 outputs ----------
__global__ __launch_bounds__(256, 1) void qkv_proj(
        const float* __restrict__ x,
        const float* __restrict__ Wq, const float* __restrict__ Wk,
        const float* __restrict__ Wv,
        _Float16* __restrict__ Qg, _Float16* __restrict__ Kg,
        _Float16* __restrict__ Vg) {
    const int t = threadIdx.x;
    const int wid = t >> 6, lane = t & 63, l15 = lane & 15, quad = lane >> 4;

    // ---- one-time: W -> B-frags (f32 load, scale Q, cvt to f16) ----
    half8 wb[3][2][4];
#pragma unroll
    for (int m = 0; m < 3; ++m) {
        const float* Wm = (m == 0) ? Wq : ((m == 1) ? Wk : Wv);
        const float sc = (m == 0) ? QSCALE : 1.0f;
#pragma unroll
        for (int kh = 0; kh < 2; ++kh)
#pragma unroll
            for (int nt = 0; nt < 4; ++nt) {
                float f[8];
#pragma unroll
                for (int j = 0; j < 8; ++j)
                    f[j] = Wm[(kh * 32 + quad * 8 + j) * 64 + nt * 16 + l15] * sc;
                union { fp16x2 h[4]; half8 v; } u;
#pragma unroll
                for (int p = 0; p < 4; ++p)
                    u.h[p] = __builtin_amdgcn_cvt_pkrtz(f[2 * p], f[2 * p + 1]);
                wb[m][kh][nt] = u.v;
            }
    }

    const int rowbase = blockIdx.x * 128 + wid * 32;
#pragma unroll
    for (int mt = 0; mt < 2; ++mt) {
        const int r0 = rowbase + mt * 16;
        // A-frags: X rows (r0+l15), f32 -> f16
        half8 xa[2];
#pragma unroll
        for (int kh = 0; kh < 2; ++kh) {
            const float* xr = x + (size_t)(r0 + l15) * 64 + kh * 32 + quad * 8;
            const float4 a = *(const float4*)xr;
            const float4 b2 = *(const float4*)(xr + 4);
            union { fp16x2 h[4]; half8 v; } u;
            u.h[0] = __builtin_amdgcn_cvt_pkrtz(a.x, a.y);
            u.h[1] = __builtin_amdgcn_cvt_pkrtz(a.z, a.w);
            u.h[2] = __builtin_amdgcn_cvt_pkrtz(b2.x, b2.y);
            u.h[3] = __builtin_amdgcn_cvt_pkrtz(b2.z, b2.w);
            xa[kh] = u.v;
        }
#pragma unroll
        for (int m = 0; m < 3; ++m) {
            f32x4 acc[4];
#pragma unroll
            for (int nt = 0; nt < 4; ++nt) {
                acc[nt] = (f32x4){0.f, 0.f, 0.f, 0.f};
                acc[nt] = __builtin_amdgcn_mfma_f32_16x16x32_f16(xa[0], wb[m][0][nt], acc[nt], 0, 0, 0);
                acc[nt] = __builtin_amdgcn_mfma_f32_16x16x32_f16(xa[1], wb[m][1][nt], acc[nt], 0, 0, 0);
            }
            _Float16* outp = (m == 0) ? Qg : ((m == 1) ? Kg : Vg);
#pragma unroll
            for (int nt = 0; nt < 4; ++nt)
#pragma unroll
                for (int j = 0; j < 4; ++j)
                    outp[(size_t)(r0 + quad * 4 + j) * 64 + nt * 16 + l15] =
                        (_Float16)acc[nt][j];
        }
    }
}

// ---------------- kernel 2: flash attention, 128q tile, 2 steps/barrier ---
// R20 = R5 step body verbatim + 4-buffer pairing (1 barrier per 2 steps).
__global__ __launch_bounds__(256, 4) void attn(
        const _Float16* __restrict__ Qg, const _Float16* __restrict__ Kg,
        const _Float16* __restrict__ Vg,
        _Float16* __restrict__ Op, float* __restrict__ Lp) {
    __shared__ __align__(16) char smem[36864];

    // decode (QT, ci): idx ascending in QT; blockIdx reversed -> heavy first
    const int idx = (NBLK2 - 1) - (int)blockIdx.x;
    int QT = 0;
    // cum(QT) table: 0,1,2,4,6,9,12,16,20,25,30,36,42,49,56,64
    QT += (idx >= 1);  QT += (idx >= 2);  QT += (idx >= 4);  QT += (idx >= 6);
    QT += (idx >= 9);  QT += (idx >= 12); QT += (idx >= 16); QT += (idx >= 20);
    QT += (idx >= 25); QT += (idx >= 30); QT += (idx >= 36); QT += (idx >= 42);
    QT += (idx >= 49); QT += (idx >= 56); QT += (idx >= 64);
    const int k2 = QT >> 1;
    const int cb = (QT & 1) ? (k2 + 1) * (k2 + 1) : k2 * (k2 + 1);
    const int ci = idx - cb;
    const int w = blockIdx.y, b = blockIdx.z;
    const int base = win_base(w), stride = win_stride(w);
    const int outblk = (b * NW + w) * NBLK2 + cb + ci;
    const int kt0 = ci * 8;                  // 32-col steps
    const int ktmax = 4 * QT + 4;
    const int kt1 = (kt0 + 8 < ktmax) ? kt0 + 8 : ktmax;   // span in {4,8}

    const _Float16* Qb = Qg + (size_t)b * NSEQ * 64;
    const _Float16* Kb = Kg + (size_t)b * NSEQ * 64;
    const _Float16* Vb = Vg + (size_t)b * NSEQ * 64;

    const int t = threadIdx.x;
    const int wid = t >> 6, lane = t & 63, l15 = lane & 15, quad = lane >> 4;

    // K staging: thread stages row sr (0..31), 16B chunk sch (XOR swizzle)
    const int sr = t >> 3, sch = t & 7;
    // V staging: thread (c4 = cols 4c4.., kq = k-pair row)
    const int c4 = t & 15, kq = t >> 4;      // kq in 0..15
    const int vd0 = 4 * c4;

    // Q frags for both strips, load once; used as MFMA *B* operand
    const size_t qr0 = (size_t)(base + stride * (QT * 128 + 16 * wid + l15)) * 64;
    const size_t qr1 = (size_t)(base + stride * (QT * 128 + 64 + 16 * wid + l15)) * 64;
    const half8 qa00 = *(const half8*)(Qb + qr0 + quad * 8);
    const half8 qa01 = *(const half8*)(Qb + qr0 + 32 + quad * 8);
    const half8 qa10 = *(const half8*)(Qb + qr1 + quad * 8);
    const half8 qa11 = *(const half8*)(Qb + qr1 + 32 + quad * 8);

    f32x4 oacc0[4], oacc1[4];
    float l0 = 0.f, l1 = 0.f;                // per-lane partial row sums
#pragma unroll
    for (int ns = 0; ns < 4; ++ns) {
        oacc0[ns] = (f32x4){0.f, 0.f, 0.f, 0.f};
        oacc1[ns] = (f32x4){0.f, 0.f, 0.f, 0.f};
    }

    half8 pk;
    u16x4 pv0, pv1;

#define LOADKV(kt)                                                           \
    {                                                                        \
        const size_t ka = (size_t)(base + stride * ((kt) * 32 + sr)) * 64 + sch * 8; \
        pk = *(const half8*)(Kb + ka);                                       \
        const size_t va = (size_t)(base + stride * ((kt) * 32 + kq)) * 64 + vd0; \
        pv0 = *(const u16x4*)(Vb + va);                                      \
        pv1 = *(const u16x4*)(Vb + va + (size_t)stride * 16 * 64);           \
    }

#define WRITEKV(koff, voff)                                                  \
    {                                                                        \
        char* Kn = smem + K_OFF + (koff);                                    \
        char* Vn = smem + VT_OFF + (voff);                                   \
        *(half8*)(Kn + sr * 128 + ((sch ^ (sr & 7)) * 16)) = pk;             \
        _Pragma("unroll")                                                    \
        for (int i = 0; i < 4; ++i) {                                        \
            int d = vd0 + i;                                                 \
            unsigned int pkw =                                               \
                (unsigned int)pv0[i] | ((unsigned int)pv1[i] << 16);         \
            int ch = ((kq >> 2) ^ (d >> 4) ^ (d & 3) ^ ((d >> 2) & 3)) & 3;  \
            *(unsigned int*)(Vn + d * VT_STRIDE + ch * 16 + (kq & 3) * 4) =  \
                pkw;                                                         \
        }                                                                    \
    }

// R5 step body verbatim (K frags from LDS, swapped QK^T, in-register P, PV)
#define COMPUTE(kt, koff, voff)                                              \
    {                                                                        \
        const char* Kd = smem + K_OFF + (koff);                              \
        const char* Vd = smem + VT_OFF + (voff);                             \
        half8 kb[2][2];                                                      \
        _Pragma("unroll")                                                    \
        for (int ns = 0; ns < 2; ++ns) {                                     \
            const int krow = ns * 16 + l15, swk = krow & 7;                  \
            kb[ns][0] = *(const half8*)(Kd + krow * 128 + ((quad ^ swk) * 16)); \
            kb[ns][1] = *(const half8*)(Kd + krow * 128 + (((quad + 4) ^ swk) * 16)); \
        }                                                                    \
        f32x4 sa0[2], sa1[2];                                                \
        __builtin_amdgcn_s_setprio(1);                                       \
        _Pragma("unroll")                                                    \
        for (int ns = 0; ns < 2; ++ns) {                                     \
            f32x4 c0 = (f32x4){0.f, 0.f, 0.f, 0.f};                          \
            c0 = __builtin_amdgcn_mfma_f32_16x16x32_f16(kb[ns][0], qa00, c0, 0, 0, 0); \
            c0 = __builtin_amdgcn_mfma_f32_16x16x32_f16(kb[ns][1], qa01, c0, 0, 0, 0); \
            sa0[ns] = c0;                                                    \
            f32x4 c1 = (f32x4){0.f, 0.f, 0.f, 0.f};                          \
            c1 = __builtin_amdgcn_mfma_f32_16x16x32_f16(kb[ns][0], qa10, c1, 0, 0, 0); \
            c1 = __builtin_amdgcn_mfma_f32_16x16x32_f16(kb[ns][1], qa11, c1, 0, 0, 0); \
            sa1[ns] = c1;                                                    \
        }                                                                    \
        __builtin_amdgcn_s_setprio(0);                                       \
        if ((kt) >= 4 * QT) {                                                \
            const int q0 = QT * 128 + 16 * wid + l15 - (kt) * 32;            \
            const int kvb = quad * 4;                                        \
            _Pragma("unroll")                                                \
            for (int ns = 0; ns < 2; ++ns)                                   \
                _Pragma("unroll")                                            \
                for (int j = 0; j < 4; ++j) {                                \
                    if (kvb + ns * 16 + j > q0)      sa0[ns][j] = -1e30f;    \
                    if (kvb + ns * 16 + j > q0 + 64) sa1[ns][j] = -1e30f;    \
                }                                                            \
        }                                                                    \
        half8 vb[4];                                                         \
        _Pragma("unroll")                                                    \
        for (int ns = 0; ns < 4; ++ns) {                                     \
            const int d = ns * 16 + l15;                                     \
            const int ch = (quad ^ (d >> 4) ^ (d & 3) ^ ((d >> 2) & 3)) & 3; \
            vb[ns] = *(const half8*)(Vd + d * VT_STRIDE + ch * 16);          \
        }                                                                    \
        {                                                                    \
            union { fp16x2 h[4]; half8 v; } pu;                              \
            _Pragma("unroll")                                                \
            for (int u = 0; u < 4; ++u) {                                    \
                float pA = EXP2(sa0[0][u] - PBIAS);                          \
                float pB = EXP2(sa0[1][u] - PBIAS);                          \
                l0 += pA + pB;                                               \
                pu.h[u] = __builtin_amdgcn_cvt_pkrtz(pA, pB);                \
            }                                                                \
            __builtin_amdgcn_s_setprio(1);                                   \
            _Pragma("unroll")                                                \
            for (int ns = 0; ns < 4; ++ns)                                   \
                oacc0[ns] = __builtin_amdgcn_mfma_f32_16x16x32_f16(pu.v, vb[ns], oacc0[ns], 0, 0, 0); \
            __builtin_amdgcn_s_setprio(0);                                   \
        }                                                                    \
        {                                                                    \
            union { fp16x2 h[4]; half8 v; } pu;                              \
            _Pragma("unroll")                                                \
            for (int u = 0; u < 4; ++u) {                                    \
                float pA = EXP2(sa1[0][u] - PBIAS);                          \
                float pB = EXP2(sa1[1][u] - PBIAS);                          \
                l1 += pA + pB;                                               \
                pu.h[u] = __builtin_amdgcn_cvt_pkrtz(pA, pB);                \
            }                                                                \
            __builtin_amdgcn_s_setprio(1);                                   \
            _Pragma("unroll")                                                \
            for (int ns = 0; ns < 4; ++ns)                                   \
                oacc1[ns] = __builtin_amdgcn_mfma_f32_16x16x32_f16(pu.v, vb[ns], oacc1[ns], 0, 0, 0); \
            __builtin_amdgcn_s_setprio(0);                                   \
        }                                                                    \
    }

    // ---- prologue: stage steps kt0, kt0+1 into pair 0 (span >= 4 always) --
    LOADKV(kt0);
    WRITEKV(0, 0);
    LOADKV(kt0 + 1);
    WRITEKV(K_BUF, VT_BUF);

    int cur = 0;   // pair selector
    for (int kt = kt0; kt < kt1; kt += 2) {
        __syncthreads();   // pair[cur] visible; pair[cur^1]'s readers done
        const int kc = cur * 2 * K_BUF;      // this pair's K base
        const int vc = cur * 2 * VT_BUF;     // this pair's V base
        const int kn = (cur ^ 1) * 2 * K_BUF;
        const int vn = (cur ^ 1) * 2 * VT_BUF;
        const bool pf2 = (kt + 2 < kt1);
        const bool pf3 = (kt + 3 < kt1);

        if (pf2) LOADKV(kt + 2);             // loads hide under step kt
        COMPUTE(kt, kc, vc);
        if (pf2) WRITEKV(kn, vn);            // vmcnt wait amortized by compute

        if (pf3) LOADKV(kt + 3);             // loads hide under step kt+1
        COMPUTE(kt + 1, kc + K_BUF, vc + VT_BUF);
        if (pf3) WRITEKV(kn + K_BUF, vn + VT_BUF);

        cur ^= 1;
    }

    // ---- epilogue: reduce l across quads, store O (f16) and linear l ----
    l0 += __shfl_xor(l0, 16, 64);
    l0 += __shfl_xor(l0, 32, 64);
    l1 += __shfl_xor(l1, 16, 64);
    l1 += __shfl_xor(l1, 32, 64);
    if (quad == 0) {
        Lp[(size_t)outblk * 128 + 16 * wid + l15]      = l0;
        Lp[(size_t)outblk * 128 + 64 + 16 * wid + l15] = l1;
    }
    const int qrow0 = 16 * wid + quad * 4;
#pragma unroll
    for (int j = 0; j < 4; ++j) {
        const float inv0 = 1.0f / __shfl(l0, quad * 4 + j, 64);
        const float inv1 = 1.0f / __shfl(l1, quad * 4 + j, 64);
        const size_t r0off = ((size_t)outblk * 128 + qrow0 + j) * 64 + l15;
        const size_t r1off = ((size_t)outblk * 128 + 64 + qrow0 + j) * 64 + l15;
#pragma unroll
        for (int ns = 0; ns < 4; ++ns) {
            Op[r0off + ns * 16] = (_Float16)(oacc0[ns][j] * inv0);
            Op[r1off + ns * 16] = (_Float16)(oacc1[ns][j] * inv1);
        }
    }
}

// ---------------- kernel 3: merge all (window, chunk) partials ------------
// Linear mix (matches the reference's alpha = denom/denom_sum): no log/exp,
// no max pass. Per group: 8 clamped-unrolled slots (cmax = j>>8 <= 7),
// inactive groups branch-skipped (masked lanes fetch nothing).
typedef _Float16 half8v __attribute__((ext_vector_type(8)));
__global__ __launch_bounds__(256) void mix_out(
        const _Float16* __restrict__ Op, const float* __restrict__ Lp,
        float* __restrict__ out) {
    int gid = blockIdx.x * 256 + threadIdx.x;   // [0, 4*8192*8)
    int f8 = gid & 7;
    int tpos = (gid >> 3) & (NSEQ - 1);
    int b = gid >> 16;

    float wsum = 0.f;
    float acc[8];
#pragma unroll
    for (int k = 0; k < 8; ++k) acc[k] = 0.f;

    // group 0: stride-1 window (always active)
    {
        int w = tpos >> 11, j = tpos & (M - 1);
        int QT = j >> 7, q = j & 127, k2 = QT >> 1;
        int cbase = (QT & 1) ? (k2 + 1) * (k2 + 1) : k2 * (k2 + 1);
        int bb = ((b * NW + w) * NBLK2 + cbase) * 128 + q;
        int cmax = j >> 8;
#pragma unroll
        for (int c = 0; c < 8; ++c) {
            int cc = (c <= cmax) ? c : cmax;
            int ix = bb + cc * 128;
            float li = Lp[ix];
            li = (c <= cmax) ? li : 0.f;
            half8v v = *(const half8v*)(Op + (size_t)ix * 64 + f8 * 8);
            wsum += li;
#pragma unroll
            for (int k = 0; k < 8; ++k) acc[k] += li * (float)v[k];
        }
    }
    // group 1: stride-2 window (active iff tpos even)
    if (!(tpos & 1)) {
        int w = 4 + (tpos >> 12), j = (tpos & 4095) >> 1;
        int QT = j >> 7, q = j & 127, k2 = QT >> 1;
        int cbase = (QT & 1) ? (k2 + 1) * (k2 + 1) : k2 * (k2 + 1);
        int bb = ((b * NW + w) * NBLK2 + cbase) * 128 + q;
        int cmax = j >> 8;
#pragma unroll
        for (int c = 0; c < 8; ++c) {
            int cc = (c <= cmax) ? c : cmax;
            int ix = bb + cc * 128;
            float li = Lp[ix];
            li = (c <= cmax) ? li : 0.f;
            half8v v = *(const half8v*)(Op + (size_t)ix * 64 + f8 * 8);
            wsum += li;
#pragma unroll
            for (int k = 0; k < 8; ++k) acc[k] += li * (float)v[k];
        }
    }
    // group 2: stride-4 window (active iff tpos % 4 == 0)
    if (!(tpos & 3)) {
        int j = tpos >> 2;
        int QT = j >> 7, q = j & 127, k2 = QT >> 1;
        int cbase = (QT & 1) ? (k2 + 1) * (k2 + 1) : k2 * (k2 + 1);
        int bb = ((b * NW + 6) * NBLK2 + cbase) * 128 + q;
        int cmax = j >> 8;
#pragma unroll
        for (int c = 0; c < 8; ++c) {
            int cc = (c <= cmax) ? c : cmax;
            int ix = bb + cc * 128;
            float li = Lp[ix];
            li = (c <= cmax) ? li : 0.f;
            half8v v = *(const half8v*)(Op + (size_t)ix * 64 + f8 * 8);
            wsum += li;
#pragma unroll
            for (int k = 0; k < 8; ++k) acc[k] += li * (float)v[k];
        }
    }

    float inv = 1.0f / wsum;
    size_t o = ((size_t)b * NSEQ + tpos) * 64 + f8 * 8;
    float4 r0 = make_float4(acc[0] * inv, acc[1] * inv, acc[2] * inv, acc[3] * inv);
    float4 r1 = make_float4(acc[4] * inv, acc[5] * inv, acc[6] * inv, acc[7] * inv);
    *(float4*)&out[o] = r0;
    *(float4*)&out[o + 4] = r1;
}

extern "C" void kernel_launch(void* const* d_in, const int* in_sizes, int n_in,
                              void* d_out, int out_size, void* d_ws, size_t ws_size,
                              hipStream_t stream) {
    const float* x  = (const float*)d_in[0];
    const float* Wq = (const float*)d_in[1];
    const float* Wk = (const float*)d_in[2];
    const float* Wv = (const float*)d_in[3];
    float* out = (float*)d_out;

    const size_t QN = (size_t)NB * NSEQ * CDIM;     // 2,097,152
    _Float16* Qg = (_Float16*)d_ws;
    _Float16* Kg = Qg + QN;
    _Float16* Vg = Kg + QN;
    _Float16* Op = Vg + QN;                         // [b][w][72][128][64] f16
    float* Lp   = (float*)(Op + (size_t)NB * NW * NBLK2 * 128 * 64);

    qkv_proj<<<NB * NSEQ / 128, 256, 0, stream>>>(x, Wq, Wk, Wv, Qg, Kg, Vg);
    attn<<<dim3(NBLK2, NW, NB), 256, 0, stream>>>(Qg, Kg, Vg, Op, Lp);
    mix_out<<<(NB * NSEQ * 8) / 256, 256, 0, stream>>>(Op, Lp, out);
}

// Round 11
// 110.138 us; speedup vs baseline: 1.7982x; 1.0887x over previous
//
#include <hip/hip_runtime.h>
#include <math.h>

#define NB   4
#define NSEQ 8192
#define CDIM 64
#define M    2048
#define NW   7
#define NBLK2 72     // 8-step kv-chunks per window: sum_QT ((QT>>1)+1) = 72

typedef _Float16 half8 __attribute__((ext_vector_type(8)));
typedef __fp16 fp16x2 __attribute__((ext_vector_type(2)));   // native cvt_pkrtz type
typedef float f32x4 __attribute__((ext_vector_type(4)));
typedef unsigned short u16x4 __attribute__((ext_vector_type(4)));

#if defined(__has_builtin) && __has_builtin(__builtin_amdgcn_exp2f)
#define EXP2(x) __builtin_amdgcn_exp2f(x)
#else
#define EXP2(x) __expf((x) * 0.69314718056f)
#endif

// Q pre-scale: 1/sqrt(64) * log2(e) folded into Wq's B-frags so attn uses raw exp2
#define QSCALE 0.1803368801111204f
// exp bias: p = exp2(s' - PBIAS) keeps P under f16 max; scales P and l by
// 2^-PBIAS uniformly -> ratios invariant in the linear mix.
#define PBIAS 4.0f

// attn LDS (18432 B total):
//   [0,8192):       K dbuf, 2 x 32 rows x 128B, XOR swizzle (conflict-free b128)
//   [8192,18432):   Vt dbuf, 2 x 64 rows x 80B stride, pair-packed
//                   pi: word u of lane-quad Q = (V[kv=4Q+u], V[kv=4Q+u+16]),
//                   chunk-XOR h(d)=(d>>4)^(d&3)^((d>>2)&3); stride 80 spreads
//                   the b32 staging writes over all 32 banks.
// THIS IS THE R5/R16 KERNEL (111.9 us), RESTORED VERBATIM. Structural bets
// that all LOST vs this baseline (measured):
//   - K-from-global w/ prefetch set: VGPR liveness >128 cap -> 216MB spill
//   - K-from-global single-set: unhidden K latency after barrier, +10us
//   - 4-buffer 2-steps/barrier: minor spill + no benefit, +8us
//   - (256,5) launch bounds: catastrophic spill (twice)
// LAUNCH BOUNDS: (256,4). DO NOT raise the 2nd arg.
#define K_OFF   0
#define VT_OFF  8192
#define VT_STRIDE 80
#define VT_BUF  5120

__device__ __forceinline__ int win_base(int w) {
    return (w < 4) ? (w << 11) : ((w < 6) ? ((w - 4) << 12) : 0);
}
__device__ __forceinline__ int win_stride(int w) {
    return (w < 4) ? 1 : ((w < 6) ? 2 : 4);
}

// ---------------- kernel 1: QKV projection via MFMA, f16 outputs ----------
__global__ __launch_bounds__(256, 1) void qkv_proj(
        const float* __restrict__ x,
        const float* __restrict__ Wq, const float* __restrict__ Wk,
        const float* __restrict__ Wv,
        _Float16* __restrict__ Qg, _Float16* __restrict__ Kg,
        _Float16* __restrict__ Vg) {
    const int t = threadIdx.x;
    const int wid = t >> 6, lane = t & 63, l15 = lane & 15, quad = lane >> 4;

    // ---- one-time: W -> B-frags (f32 load, scale Q, cvt to f16) ----
    half8 wb[3][2][4];
#pragma unroll
    for (int m = 0; m < 3; ++m) {
        const float* Wm = (m == 0) ? Wq : ((m == 1) ? Wk : Wv);
        const float sc = (m == 0) ? QSCALE : 1.0f;
#pragma unroll
        for (int kh = 0; kh < 2; ++kh)
#pragma unroll
            for (int nt = 0; nt < 4; ++nt) {
                float f[8];
#pragma unroll
                for (int j = 0; j < 8; ++j)
                    f[j] = Wm[(kh * 32 + quad * 8 + j) * 64 + nt * 16 + l15] * sc;
                union { fp16x2 h[4]; half8 v; } u;
#pragma unroll
                for (int p = 0; p < 4; ++p)
                    u.h[p] = __builtin_amdgcn_cvt_pkrtz(f[2 * p], f[2 * p + 1]);
                wb[m][kh][nt] = u.v;
            }
    }

    const int rowbase = blockIdx.x * 128 + wid * 32;
#pragma unroll
    for (int mt = 0; mt < 2; ++mt) {
        const int r0 = rowbase + mt * 16;
        // A-frags: X rows (r0+l15), f32 -> f16
        half8 xa[2];
#pragma unroll
        for (int kh = 0; kh < 2; ++kh) {
            const float* xr = x + (size_t)(r0 + l15) * 64 + kh * 32 + quad * 8;
            const float4 a = *(const float4*)xr;
            const float4 b2 = *(const float4*)(xr + 4);
            union { fp16x2 h[4]; half8 v; } u;
            u.h[0] = __builtin_amdgcn_cvt_pkrtz(a.x, a.y);
            u.h[1] = __builtin_amdgcn_cvt_pkrtz(a.z, a.w);
            u.h[2] = __builtin_amdgcn_cvt_pkrtz(b2.x, b2.y);
            u.h[3] = __builtin_amdgcn_cvt_pkrtz(b2.z, b2.w);
            xa[kh] = u.v;
        }
#pragma unroll
        for (int m = 0; m < 3; ++m) {
            f32x4 acc[4];
#pragma unroll
            for (int nt = 0; nt < 4; ++nt) {
                acc[nt] = (f32x4){0.f, 0.f, 0.f, 0.f};
                acc[nt] = __builtin_amdgcn_mfma_f32_16x16x32_f16(xa[0], wb[m][0][nt], acc[nt], 0, 0, 0);
                acc[nt] = __builtin_amdgcn_mfma_f32_16x16x32_f16(xa[1], wb[m][1][nt], acc[nt], 0, 0, 0);
            }
            _Float16* outp = (m == 0) ? Qg : ((m == 1) ? Kg : Vg);
#pragma unroll
            for (int nt = 0; nt < 4; ++nt)
#pragma unroll
                for (int j = 0; j < 4; ++j)
                    outp[(size_t)(r0 + quad * 4 + j) * 64 + nt * 16 + l15] =
                        (_Float16)acc[nt][j];
        }
    }
}

// ---------------- kernel 2: flash attention, 128q tile x 8 k-steps --------
// 8-step kv-chunks; K+V LDS dbuf; 1 barrier/step; swapped QK^T (mfma(K,Q))
// so each lane holds its PV A-frag in registers (no Ps LDS round-trip);
// linear partial weights (no log/exp in the merge path).
__global__ __launch_bounds__(256, 4) void attn(
        const _Float16* __restrict__ Qg, const _Float16* __restrict__ Kg,
        const _Float16* __restrict__ Vg,
        _Float16* __restrict__ Op, float* __restrict__ Lp) {
    __shared__ __align__(16) char smem[18432];

    // decode (QT, ci): idx ascending in QT; blockIdx reversed -> heavy first
    const int idx = (NBLK2 - 1) - (int)blockIdx.x;
    int QT = 0;
    // cum(QT) table: 0,1,2,4,6,9,12,16,20,25,30,36,42,49,56,64 (compare chain,
    // literals only — no runtime-indexed array -> no scratch)
    QT += (idx >= 1);  QT += (idx >= 2);  QT += (idx >= 4);  QT += (idx >= 6);
    QT += (idx >= 9);  QT += (idx >= 12); QT += (idx >= 16); QT += (idx >= 20);
    QT += (idx >= 25); QT += (idx >= 30); QT += (idx >= 36); QT += (idx >= 42);
    QT += (idx >= 49); QT += (idx >= 56); QT += (idx >= 64);
    const int k2 = QT >> 1;
    const int cb = (QT & 1) ? (k2 + 1) * (k2 + 1) : k2 * (k2 + 1);
    const int ci = idx - cb;
    const int w = blockIdx.y, b = blockIdx.z;
    const int base = win_base(w), stride = win_stride(w);
    const int outblk = (b * NW + w) * NBLK2 + cb + ci;
    const int kt0 = ci * 8;                  // 32-col steps
    const int ktmax = 4 * QT + 4;
    const int kt1 = (kt0 + 8 < ktmax) ? kt0 + 8 : ktmax;

    const _Float16* Qb = Qg + (size_t)b * NSEQ * 64;
    const _Float16* Kb = Kg + (size_t)b * NSEQ * 64;
    const _Float16* Vb = Vg + (size_t)b * NSEQ * 64;

    const int t = threadIdx.x;
    const int wid = t >> 6, lane = t & 63, l15 = lane & 15, quad = lane >> 4;

    // K staging: thread stages row sr (0..31), 16B chunk sch (XOR swizzle)
    const int sr = t >> 3, sch = t & 7;
    // V staging: thread (c4 = cols 4c4.., kq = k-pair row)
    const int c4 = t & 15, kq = t >> 4;      // kq in 0..15
    const int vd0 = 4 * c4;

    // Q frags for both strips, load once; used as MFMA *B* operand
    const size_t qr0 = (size_t)(base + stride * (QT * 128 + 16 * wid + l15)) * 64;
    const size_t qr1 = (size_t)(base + stride * (QT * 128 + 64 + 16 * wid + l15)) * 64;
    const half8 qa00 = *(const half8*)(Qb + qr0 + quad * 8);
    const half8 qa01 = *(const half8*)(Qb + qr0 + 32 + quad * 8);
    const half8 qa10 = *(const half8*)(Qb + qr1 + quad * 8);
    const half8 qa11 = *(const half8*)(Qb + qr1 + 32 + quad * 8);

    f32x4 oacc0[4], oacc1[4];
    float l0 = 0.f, l1 = 0.f;                // per-lane partial row sums
#pragma unroll
    for (int ns = 0; ns < 4; ++ns) {
        oacc0[ns] = (f32x4){0.f, 0.f, 0.f, 0.f};
        oacc1[ns] = (f32x4){0.f, 0.f, 0.f, 0.f};
    }

    half8 pk;
    u16x4 pv0, pv1;

    // ---- prologue: stage step kt0 into buffer 0 ----
    {
        const size_t ka = (size_t)(base + stride * (kt0 * 32 + sr)) * 64 + sch * 8;
        pk = *(const half8*)(Kb + ka);
        const size_t va = (size_t)(base + stride * (kt0 * 32 + kq)) * 64 + vd0;
        pv0 = *(const u16x4*)(Vb + va);
        pv1 = *(const u16x4*)(Vb + va + (size_t)stride * 16 * 64);
        char* Kd = smem + K_OFF;
        char* Vd = smem + VT_OFF;
        *(half8*)(Kd + sr * 128 + ((sch ^ (sr & 7)) * 16)) = pk;
#pragma unroll
        for (int i = 0; i < 4; ++i) {
            int d = vd0 + i;
            unsigned int pkw = (unsigned int)pv0[i] | ((unsigned int)pv1[i] << 16);
            int ch = ((kq >> 2) ^ (d >> 4) ^ (d & 3) ^ ((d >> 2) & 3)) & 3;
            *(unsigned int*)(Vd + d * VT_STRIDE + ch * 16 + (kq & 3) * 4) = pkw;
        }
    }

    int cur = 0;
    for (int kt = kt0; kt < kt1; ++kt) {
        __syncthreads();   // buf[cur] visible; all reads of buf[cur^1] done
        const bool pf = (kt + 1 < kt1);
        if (pf) {   // prefetch next step (consumed at end of this iteration)
            const size_t ka = (size_t)(base + stride * ((kt + 1) * 32 + sr)) * 64 + sch * 8;
            pk = *(const half8*)(Kb + ka);
            const size_t va = (size_t)(base + stride * ((kt + 1) * 32 + kq)) * 64 + vd0;
            pv0 = *(const u16x4*)(Vb + va);
            pv1 = *(const u16x4*)(Vb + va + (size_t)stride * 16 * 64);
        }

        const char* Kd = smem + K_OFF + cur * 4096;
        const char* Vd = smem + VT_OFF + cur * VT_BUF;

        // ---- K frags (read ONCE, used by both strips) ----
        half8 kb[2][2];
#pragma unroll
        for (int ns = 0; ns < 2; ++ns) {
            const int krow = ns * 16 + l15, swk = krow & 7;
            kb[ns][0] = *(const half8*)(Kd + krow * 128 + ((quad ^ swk) * 16));
            kb[ns][1] = *(const half8*)(Kd + krow * 128 + (((quad + 4) ^ swk) * 16));
        }
        // ---- swapped QK^T: S^T[kv_local=ns*16+quad*4+j][q=l15] ----
        f32x4 sa0[2], sa1[2];
        __builtin_amdgcn_s_setprio(1);
#pragma unroll
        for (int ns = 0; ns < 2; ++ns) {
            f32x4 c0 = (f32x4){0.f, 0.f, 0.f, 0.f};
            c0 = __builtin_amdgcn_mfma_f32_16x16x32_f16(kb[ns][0], qa00, c0, 0, 0, 0);
            c0 = __builtin_amdgcn_mfma_f32_16x16x32_f16(kb[ns][1], qa01, c0, 0, 0, 0);
            sa0[ns] = c0;
            f32x4 c1 = (f32x4){0.f, 0.f, 0.f, 0.f};
            c1 = __builtin_amdgcn_mfma_f32_16x16x32_f16(kb[ns][0], qa10, c1, 0, 0, 0);
            c1 = __builtin_amdgcn_mfma_f32_16x16x32_f16(kb[ns][1], qa11, c1, 0, 0, 0);
            sa1[ns] = c1;
        }
        __builtin_amdgcn_s_setprio(0);
        if (kt >= 4 * QT) {   // causal region (last 4 steps of the tile)
            const int q0 = QT * 128 + 16 * wid + l15 - kt * 32;  // vs kv_local
            const int kvb = quad * 4;
#pragma unroll
            for (int ns = 0; ns < 2; ++ns)
#pragma unroll
                for (int j = 0; j < 4; ++j) {
                    if (kvb + ns * 16 + j > q0)      sa0[ns][j] = -1e30f;
                    if (kvb + ns * 16 + j > q0 + 64) sa1[ns][j] = -1e30f;
                }
        }

        // ---- Vt B-frags read ONCE, reused by both strips' PV ----
        half8 vb[4];
#pragma unroll
        for (int ns = 0; ns < 4; ++ns) {
            const int d = ns * 16 + l15;
            const int ch = (quad ^ (d >> 4) ^ (d & 3) ^ ((d >> 2) & 3)) & 3;
            vb[ns] = *(const half8*)(Vd + d * VT_STRIDE + ch * 16);
        }

        // ---- strip0: exp2 + in-register pack -> PV (NO LDS round-trip) ----
        {
            union { fp16x2 h[4]; half8 v; } pu;
#pragma unroll
            for (int u = 0; u < 4; ++u) {
                float pA = EXP2(sa0[0][u] - PBIAS);   // kv = 4*quad+u
                float pB = EXP2(sa0[1][u] - PBIAS);   // kv = 4*quad+u+16
                l0 += pA + pB;
                pu.h[u] = __builtin_amdgcn_cvt_pkrtz(pA, pB);
            }
            __builtin_amdgcn_s_setprio(1);
#pragma unroll
            for (int ns = 0; ns < 4; ++ns)
                oacc0[ns] = __builtin_amdgcn_mfma_f32_16x16x32_f16(pu.v, vb[ns], oacc0[ns], 0, 0, 0);
            __builtin_amdgcn_s_setprio(0);
        }
        // ---- strip1 ----
        {
            union { fp16x2 h[4]; half8 v; } pu;
#pragma unroll
            for (int u = 0; u < 4; ++u) {
                float pA = EXP2(sa1[0][u] - PBIAS);
                float pB = EXP2(sa1[1][u] - PBIAS);
                l1 += pA + pB;
                pu.h[u] = __builtin_amdgcn_cvt_pkrtz(pA, pB);
            }
            __builtin_amdgcn_s_setprio(1);
#pragma unroll
            for (int ns = 0; ns < 4; ++ns)
                oacc1[ns] = __builtin_amdgcn_mfma_f32_16x16x32_f16(pu.v, vb[ns], oacc1[ns], 0, 0, 0);
            __builtin_amdgcn_s_setprio(0);
        }

        // ---- write prefetched step into the other buffer ----
        if (pf) {
            char* Kn = smem + K_OFF + (cur ^ 1) * 4096;
            char* Vn = smem + VT_OFF + (cur ^ 1) * VT_BUF;
            *(half8*)(Kn + sr * 128 + ((sch ^ (sr & 7)) * 16)) = pk;
#pragma unroll
            for (int i = 0; i < 4; ++i) {
                int d = vd0 + i;
                unsigned int pkw = (unsigned int)pv0[i] | ((unsigned int)pv1[i] << 16);
                int ch = ((kq >> 2) ^ (d >> 4) ^ (d & 3) ^ ((d >> 2) & 3)) & 3;
                *(unsigned int*)(Vn + d * VT_STRIDE + ch * 16 + (kq & 3) * 4) = pkw;
            }
        }
        cur ^= 1;
    }

    // ---- epilogue: reduce l across quads, store O (f16) and linear l ----
    l0 += __shfl_xor(l0, 16, 64);
    l0 += __shfl_xor(l0, 32, 64);
    l1 += __shfl_xor(l1, 16, 64);
    l1 += __shfl_xor(l1, 32, 64);
    if (quad == 0) {
        Lp[(size_t)outblk * 128 + 16 * wid + l15]      = l0;
        Lp[(size_t)outblk * 128 + 64 + 16 * wid + l15] = l1;
    }
    const int qrow0 = 16 * wid + quad * 4;
#pragma unroll
    for (int j = 0; j < 4; ++j) {
        const float inv0 = 1.0f / __shfl(l0, quad * 4 + j, 64);
        const float inv1 = 1.0f / __shfl(l1, quad * 4 + j, 64);
        const size_t r0off = ((size_t)outblk * 128 + qrow0 + j) * 64 + l15;
        const size_t r1off = ((size_t)outblk * 128 + 64 + qrow0 + j) * 64 + l15;
#pragma unroll
        for (int ns = 0; ns < 4; ++ns) {
            Op[r0off + ns * 16] = (_Float16)(oacc0[ns][j] * inv0);
            Op[r1off + ns * 16] = (_Float16)(oacc1[ns][j] * inv1);
        }
    }
}

// ---------------- kernel 3: merge all (window, chunk) partials ------------
// Linear mix (matches the reference's alpha = denom/denom_sum): no log/exp,
// no max pass. Per group: 8 clamped-unrolled slots (cmax = j>>8 <= 7),
// inactive groups branch-skipped (masked lanes fetch nothing).
typedef _Float16 half8v __attribute__((ext_vector_type(8)));
__global__ __launch_bounds__(256) void mix_out(
        const _Float16* __restrict__ Op, const float* __restrict__ Lp,
        float* __restrict__ out) {
    int gid = blockIdx.x * 256 + threadIdx.x;   // [0, 4*8192*8)
    int f8 = gid & 7;
    int tpos = (gid >> 3) & (NSEQ - 1);
    int b = gid >> 16;

    float wsum = 0.f;
    float acc[8];
#pragma unroll
    for (int k = 0; k < 8; ++k) acc[k] = 0.f;

    // group 0: stride-1 window (always active)
    {
        int w = tpos >> 11, j = tpos & (M - 1);
        int QT = j >> 7, q = j & 127, k2 = QT >> 1;
        int cbase = (QT & 1) ? (k2 + 1) * (k2 + 1) : k2 * (k2 + 1);
        int bb = ((b * NW + w) * NBLK2 + cbase) * 128 + q;
        int cmax = j >> 8;
#pragma unroll
        for (int c = 0; c < 8; ++c) {
            int cc = (c <= cmax) ? c : cmax;
            int ix = bb + cc * 128;
            float li = Lp[ix];
            li = (c <= cmax) ? li : 0.f;
            half8v v = *(const half8v*)(Op + (size_t)ix * 64 + f8 * 8);
            wsum += li;
#pragma unroll
            for (int k = 0; k < 8; ++k) acc[k] += li * (float)v[k];
        }
    }
    // group 1: stride-2 window (active iff tpos even)
    if (!(tpos & 1)) {
        int w = 4 + (tpos >> 12), j = (tpos & 4095) >> 1;
        int QT = j >> 7, q = j & 127, k2 = QT >> 1;
        int cbase = (QT & 1) ? (k2 + 1) * (k2 + 1) : k2 * (k2 + 1);
        int bb = ((b * NW + w) * NBLK2 + cbase) * 128 + q;
        int cmax = j >> 8;
#pragma unroll
        for (int c = 0; c < 8; ++c) {
            int cc = (c <= cmax) ? c : cmax;
            int ix = bb + cc * 128;
            float li = Lp[ix];
            li = (c <= cmax) ? li : 0.f;
            half8v v = *(const half8v*)(Op + (size_t)ix * 64 + f8 * 8);
            wsum += li;
#pragma unroll
            for (int k = 0; k < 8; ++k) acc[k] += li * (float)v[k];
        }
    }
    // group 2: stride-4 window (active iff tpos % 4 == 0)
    if (!(tpos & 3)) {
        int j = tpos >> 2;
        int QT = j >> 7, q = j & 127, k2 = QT >> 1;
        int cbase = (QT & 1) ? (k2 + 1) * (k2 + 1) : k2 * (k2 + 1);
        int bb = ((b * NW + 6) * NBLK2 + cbase) * 128 + q;
        int cmax = j >> 8;
#pragma unroll
        for (int c = 0; c < 8; ++c) {
            int cc = (c <= cmax) ? c : cmax;
            int ix = bb + cc * 128;
            float li = Lp[ix];
            li = (c <= cmax) ? li : 0.f;
            half8v v = *(const half8v*)(Op + (size_t)ix * 64 + f8 * 8);
            wsum += li;
#pragma unroll
            for (int k = 0; k < 8; ++k) acc[k] += li * (float)v[k];
        }
    }

    float inv = 1.0f / wsum;
    size_t o = ((size_t)b * NSEQ + tpos) * 64 + f8 * 8;
    float4 r0 = make_float4(acc[0] * inv, acc[1] * inv, acc[2] * inv, acc[3] * inv);
    float4 r1 = make_float4(acc[4] * inv, acc[5] * inv, acc[6] * inv, acc[7] * inv);
    *(float4*)&out[o] = r0;
    *(float4*)&out[o + 4] = r1;
}

extern "C" void kernel_launch(void* const* d_in, const int* in_sizes, int n_in,
                              void* d_out, int out_size, void* d_ws, size_t ws_size,
                              hipStream_t stream) {
    const float* x  = (const float*)d_in[0];
    const float* Wq = (const float*)d_in[1];
    const float* Wk = (const float*)d_in[2];
    const float* Wv = (const float*)d_in[3];
    float* out = (float*)d_out;

    const size_t QN = (size_t)NB * NSEQ * CDIM;     // 2,097,152
    _Float16* Qg = (_Float16*)d_ws;
    _Float16* Kg = Qg + QN;
    _Float16* Vg = Kg + QN;
    _Float16* Op = Vg + QN;                         // [b][w][72][128][64] f16
    float* Lp   = (float*)(Op + (size_t)NB * NW * NBLK2 * 128 * 64);

    qkv_proj<<<NB * NSEQ / 128, 256, 0, stream>>>(x, Wq, Wk, Wv, Qg, Kg, Vg);
    attn<<<dim3(NBLK2, NW, NB), 256, 0, stream>>>(Qg, Kg, Vg, Op, Lp);
    mix_out<<<(NB * NSEQ * 8) / 256, 256, 0, stream>>>(Op, Lp, out);
}